// Round 1
// baseline (1327.838 us; speedup 1.0000x reference)
//
#include <hip/hip_runtime.h>
#include <cstdint>
#include <math.h>

typedef unsigned short u16;
typedef __attribute__((ext_vector_type(8))) short bf16x8;  // 8 bf16 (4 VGPRs)
typedef __attribute__((ext_vector_type(4))) float f32x4;   // MFMA acc

#define DEVI __device__ __forceinline__

DEVI u16 f2bf(float f) {
  union { float f; uint32_t u; } v; v.f = f;
  return (u16)((v.u + 0x7FFFu + ((v.u >> 16) & 1u)) >> 16);  // RNE
}
DEVI float bf2f(u16 h) {
  union { uint32_t u; float f; } v; v.u = ((uint32_t)h) << 16;
  return v.f;
}

// ---------------------------------------------------------------------------
// GEMM: C[M,N] = act(A[M,K] @ B[K,N] + bias), bf16 MFMA, fp32 accumulate.
// 128x128 tile, BK=32, 256 threads (4 waves, each 64x64 = 4x4 of 16x16x32).
// A: fp32 or bf16 global (cvt in staging). B: fp32 global. C: fp32 or bf16.
// LDS: As[m][k], Bs[n][k] (transposed), row stride 40 (20 banks -> 2-way free).
// ---------------------------------------------------------------------------
template<bool A_BF16, bool C_BF16, bool GELU_ACT>
__global__ __launch_bounds__(256, 2)
void gemm_kernel(const void* __restrict__ Av, const float* __restrict__ Bm,
                 const float* __restrict__ bias, void* __restrict__ Cv,
                 int M, int N, int Kd)
{
  (void)M;
  __shared__ u16 As[128 * 40];
  __shared__ u16 Bs[128 * 40];
  const int tid = threadIdx.x;
  const int m0 = blockIdx.y * 128;
  const int n0 = blockIdx.x * 128;
  const int w = tid >> 6, lane = tid & 63;
  const int wm = (w >> 1) * 64, wn = (w & 1) * 64;
  const int mr = lane & 15, ko = (lane >> 4) * 8;  // frag: row=lane&15, k=quad*8+j

  f32x4 acc[4][4];
#pragma unroll
  for (int i = 0; i < 4; ++i)
#pragma unroll
    for (int j = 0; j < 4; ++j) {
      f32x4 z = {0.f, 0.f, 0.f, 0.f};
      acc[i][j] = z;
    }

  const float* Af = (const float*)Av;
  const u16*   Ah = (const u16*)Av;

  const int ar = tid >> 3;        // 0..31 (A row within pass)
  const int ak = (tid & 7) * 4;   // 0..28 (A k offset)
  const int bk = tid >> 5;        // 0..7  (B k within pass)
  const int bn = (tid & 31) * 4;  // 0..124 (B n offset)

  for (int k0 = 0; k0 < Kd; k0 += 32) {
    // stage A tile: 128 rows x 32 k
#pragma unroll
    for (int p = 0; p < 4; ++p) {
      int row = p * 32 + ar;
      if (A_BF16) {
        uint2 u = *(const uint2*)(Ah + (size_t)(m0 + row) * Kd + k0 + ak);
        *(uint2*)&As[row * 40 + ak] = u;
      } else {
        float4 f = *(const float4*)(Af + (size_t)(m0 + row) * Kd + k0 + ak);
        uint32_t lo = (uint32_t)f2bf(f.x) | ((uint32_t)f2bf(f.y) << 16);
        uint32_t hi = (uint32_t)f2bf(f.z) | ((uint32_t)f2bf(f.w) << 16);
        *(uint2*)&As[row * 40 + ak] = make_uint2(lo, hi);
      }
    }
    // stage B tile transposed: Bs[n][k]
#pragma unroll
    for (int p = 0; p < 4; ++p) {
      int kk = p * 8 + bk;
      float4 f = *(const float4*)(Bm + (size_t)(k0 + kk) * N + n0 + bn);
      Bs[(bn + 0) * 40 + kk] = f2bf(f.x);
      Bs[(bn + 1) * 40 + kk] = f2bf(f.y);
      Bs[(bn + 2) * 40 + kk] = f2bf(f.z);
      Bs[(bn + 3) * 40 + kk] = f2bf(f.w);
    }
    __syncthreads();
    bf16x8 af[4], bfr[4];
#pragma unroll
    for (int i = 0; i < 4; ++i)
      af[i] = *(const bf16x8*)&As[(wm + i * 16 + mr) * 40 + ko];
#pragma unroll
    for (int i = 0; i < 4; ++i)
      bfr[i] = *(const bf16x8*)&Bs[(wn + i * 16 + mr) * 40 + ko];
#pragma unroll
    for (int i = 0; i < 4; ++i)
#pragma unroll
      for (int j = 0; j < 4; ++j)
        acc[i][j] = __builtin_amdgcn_mfma_f32_16x16x32_bf16(af[i], bfr[j], acc[i][j], 0, 0, 0);
    __syncthreads();
  }

  // epilogue: C/D layout row=(lane>>4)*4+r, col=lane&15 (m89/m91-verified)
  const int rq = (lane >> 4) * 4;
#pragma unroll
  for (int i = 0; i < 4; ++i) {
    int rbase = m0 + wm + i * 16 + rq;
#pragma unroll
    for (int j = 0; j < 4; ++j) {
      int col = n0 + wn + j * 16 + mr;
      float bv = bias[col];
#pragma unroll
      for (int r = 0; r < 4; ++r) {
        float v = acc[i][j][r] + bv;
        if (GELU_ACT) v = 0.5f * v * (1.f + erff(v * 0.70710678118654752f));
        size_t off = (size_t)(rbase + r) * N + col;
        if (C_BF16) ((u16*)Cv)[off] = f2bf(v);
        else        ((float*)Cv)[off] = v;
      }
    }
  }
}

// ---------------------------------------------------------------------------
// Banded flash attention: block = (b, h, 64-query tile), 256 thr (4 waves).
// Wave w owns queries w*16..w*16+15. 9 key chunks of 64 (window +-256).
// QK^T with lane=t; online softmax; P transposed through LDS; PV with lane=d.
// Q pre-scaled by 1/sqrt(2048) (reference scales by sqrt(seq_len)).
// ---------------------------------------------------------------------------
__global__ __launch_bounds__(256)
void attn_kernel(const u16* __restrict__ Q, const u16* __restrict__ Kx,
                 const u16* __restrict__ V, u16* __restrict__ ctx)
{
  const int KS = 2048, HD = 1024;
  const int qt = blockIdx.x, hh = blockIdx.y, bb = blockIdx.z;
  const int s0 = qt * 64;
  const int tid = threadIdx.x, w = tid >> 6, lane = tid & 63;

  __shared__ float Qs[64 * 68];
  __shared__ float Ks[64 * 68];
  __shared__ float Vs[64 * 68];
  __shared__ float Ps[64 * 68];

  const float qscale = 0.022097086912079608f;  // 1/sqrt(2048)
  const int sr = tid >> 3;         // 0..31
  const int sd = (tid & 7) * 8;    // 0..56

  // stage Q (scaled) -> Qs[q][d]
#pragma unroll
  for (int p = 0; p < 2; ++p) {
    int row = p * 32 + sr;
    const u16* src = Q + (size_t)(bb * KS + s0 + row) * HD + hh * 64 + sd;
    uint4 u = *(const uint4*)src;
    uint32_t uu[4] = {u.x, u.y, u.z, u.w};
#pragma unroll
    for (int j = 0; j < 4; ++j) {
      Qs[row * 68 + sd + 2 * j]     = bf2f((u16)(uu[j] & 0xFFFFu)) * qscale;
      Qs[row * 68 + sd + 2 * j + 1] = bf2f((u16)(uu[j] >> 16)) * qscale;
    }
  }

  float m_[16], l_[16], O[16], Al[16];
#pragma unroll
  for (int q = 0; q < 16; ++q) { m_[q] = -INFINITY; l_[q] = 0.f; O[q] = 0.f; }

  for (int c = 0; c < 9; ++c) {
    int tb = s0 - 256 + c * 64;
    if (tb + 64 <= 0 || tb >= KS) continue;  // block-uniform skip
    __syncthreads();                          // protect LDS from prev PV reads
    // stage K/V chunk (zero-fill OOB rows: LDS always fully defined)
#pragma unroll
    for (int p = 0; p < 2; ++p) {
      int row = p * 32 + sr;
      int t = tb + row;
      if (t >= 0 && t < KS) {
        const u16* ksrc = Kx + (size_t)(bb * KS + t) * HD + hh * 64 + sd;
        const u16* vsrc = V  + (size_t)(bb * KS + t) * HD + hh * 64 + sd;
        uint4 uk = *(const uint4*)ksrc;
        uint4 uv = *(const uint4*)vsrc;
        uint32_t a4[4] = {uk.x, uk.y, uk.z, uk.w};
        uint32_t b4[4] = {uv.x, uv.y, uv.z, uv.w};
#pragma unroll
        for (int j = 0; j < 4; ++j) {
          Ks[row * 68 + sd + 2 * j]     = bf2f((u16)(a4[j] & 0xFFFFu));
          Ks[row * 68 + sd + 2 * j + 1] = bf2f((u16)(a4[j] >> 16));
          Vs[row * 68 + sd + 2 * j]     = bf2f((u16)(b4[j] & 0xFFFFu));
          Vs[row * 68 + sd + 2 * j + 1] = bf2f((u16)(b4[j] >> 16));
        }
      } else {
#pragma unroll
        for (int j = 0; j < 8; ++j) {
          Ks[row * 68 + sd + j] = 0.f;
          Vs[row * 68 + sd + j] = 0.f;
        }
      }
    }
    __syncthreads();

    // scores: lane = key t within chunk
    float S[16];
#pragma unroll
    for (int q = 0; q < 16; ++q) S[q] = 0.f;
    for (int d4 = 0; d4 < 16; ++d4) {
      float4 kv = *(const float4*)&Ks[lane * 68 + d4 * 4];
#pragma unroll
      for (int q = 0; q < 16; ++q) {
        float4 qv = *(const float4*)&Qs[(w * 16 + q) * 68 + d4 * 4];
        S[q] += qv.x * kv.x + qv.y * kv.y + qv.z * kv.z + qv.w * kv.w;
      }
    }
    const int tg = tb + lane;
#pragma unroll
    for (int q = 0; q < 16; ++q) {
      int sg = s0 + w * 16 + q;
      int diff = sg - tg;
      bool valid = (tg >= 0) && (tg < KS) && (diff <= 256) && (diff >= -256);
      float sc = valid ? S[q] : -INFINITY;
      float mx = sc;
#pragma unroll
      for (int o = 32; o > 0; o >>= 1) mx = fmaxf(mx, __shfl_xor(mx, o, 64));
      float mnew = fmaxf(m_[q], mx);
      float p = expf(sc - mnew);         // -inf -> 0
      float sum = p;
#pragma unroll
      for (int o = 32; o > 0; o >>= 1) sum += __shfl_xor(sum, o, 64);
      Al[q] = expf(m_[q] - mnew);        // first chunk: exp(-inf)=0
      l_[q] = l_[q] * Al[q] + sum;
      m_[q] = mnew;
      Ps[(w * 16 + q) * 68 + lane] = p;  // transpose P through LDS
    }
    __syncthreads();
    // PV: lane = output dim d
#pragma unroll
    for (int q = 0; q < 16; ++q) O[q] *= Al[q];
    for (int t4 = 0; t4 < 16; ++t4) {
      float v0 = Vs[(t4 * 4 + 0) * 68 + lane];
      float v1 = Vs[(t4 * 4 + 1) * 68 + lane];
      float v2 = Vs[(t4 * 4 + 2) * 68 + lane];
      float v3 = Vs[(t4 * 4 + 3) * 68 + lane];
#pragma unroll
      for (int q = 0; q < 16; ++q) {
        float4 pv = *(const float4*)&Ps[(w * 16 + q) * 68 + t4 * 4];
        O[q] += pv.x * v0 + pv.y * v1 + pv.z * v2 + pv.w * v3;
      }
    }
  }
#pragma unroll
  for (int q = 0; q < 16; ++q) {
    int sg = s0 + w * 16 + q;
    float o = O[q] / l_[q];
    ctx[(size_t)(bb * KS + sg) * HD + hh * 64 + lane] = f2bf(o);
  }
}

// ---------------------------------------------------------------------------
// LayerNorm(a + b) over D=1024, one block per row, 256 threads (float4 each).
// ---------------------------------------------------------------------------
__global__ __launch_bounds__(256)
void ln_kernel(const float* __restrict__ a, const float* __restrict__ b,
               const float* __restrict__ g, const float* __restrict__ be,
               float* __restrict__ out)
{
  __shared__ float red[8];
  const int row = blockIdx.x, tid = threadIdx.x;
  const int w = tid >> 6, lane = tid & 63;
  size_t base = (size_t)row * 1024 + tid * 4;
  float4 va = *(const float4*)(a + base);
  float4 vb = *(const float4*)(b + base);
  float v0 = va.x + vb.x, v1 = va.y + vb.y, v2 = va.z + vb.z, v3 = va.w + vb.w;
  float s1 = v0 + v1 + v2 + v3;
  float s2 = v0 * v0 + v1 * v1 + v2 * v2 + v3 * v3;
#pragma unroll
  for (int o = 32; o > 0; o >>= 1) {
    s1 += __shfl_xor(s1, o, 64);
    s2 += __shfl_xor(s2, o, 64);
  }
  if (lane == 0) { red[w] = s1; red[4 + w] = s2; }
  __syncthreads();
  s1 = red[0] + red[1] + red[2] + red[3];
  s2 = red[4] + red[5] + red[6] + red[7];
  float mu = s1 * (1.f / 1024.f);
  float var = s2 * (1.f / 1024.f) - mu * mu;
  float rs = rsqrtf(var + 1e-5f);
  float4 gv = *(const float4*)(g + tid * 4);
  float4 bv = *(const float4*)(be + tid * 4);
  float4 ov;
  ov.x = (v0 - mu) * rs * gv.x + bv.x;
  ov.y = (v1 - mu) * rs * gv.y + bv.y;
  ov.z = (v2 - mu) * rs * gv.z + bv.z;
  ov.w = (v3 - mu) * rs * gv.w + bv.w;
  *(float4*)(out + base) = ov;
}

// ---------------------------------------------------------------------------
// ws layout (64 MiB total):
//   [0      , 8 MiB)  Q  bf16   \
//   [8 MiB  , 16 MiB) K  bf16    \  reused as h (4096x4096 bf16, 32 MiB)
//   [16 MiB , 24 MiB) V  bf16    /  after attention+Wo are done
//   [24 MiB , 32 MiB) ctx bf16  /
//   [32 MiB , 48 MiB) sa fp32  -> reused as y
//   [48 MiB , 64 MiB) x1 fp32
// ---------------------------------------------------------------------------
extern "C" void kernel_launch(void* const* d_in, const int* in_sizes, int n_in,
                              void* d_out, int out_size, void* d_ws, size_t ws_size,
                              hipStream_t stream)
{
  (void)in_sizes; (void)n_in; (void)out_size; (void)ws_size;
  const float* x   = (const float*)d_in[0];
  const float* Wq  = (const float*)d_in[1];
  const float* bq  = (const float*)d_in[2];
  const float* Wk  = (const float*)d_in[3];
  const float* bk  = (const float*)d_in[4];
  const float* Wv  = (const float*)d_in[5];
  const float* bv  = (const float*)d_in[6];
  const float* Wo  = (const float*)d_in[7];
  const float* bo  = (const float*)d_in[8];
  const float* W1  = (const float*)d_in[9];
  const float* b1  = (const float*)d_in[10];
  const float* W2  = (const float*)d_in[11];
  const float* b2  = (const float*)d_in[12];
  const float* g1  = (const float*)d_in[13];
  const float* be1 = (const float*)d_in[14];
  const float* g2  = (const float*)d_in[15];
  const float* be2 = (const float*)d_in[16];

  char* ws = (char*)d_ws;
  const size_t MB8 = 8388608;
  u16*   Qb = (u16*)(ws + 0 * MB8);
  u16*   Kb = (u16*)(ws + 1 * MB8);
  u16*   Vb = (u16*)(ws + 2 * MB8);
  u16*   Cb = (u16*)(ws + 3 * MB8);
  u16*   Hb = (u16*)(ws + 0 * MB8);       // overlays Q..ctx (dead by then)
  float* SA = (float*)(ws + 4 * MB8);     // sa, later y
  float* X1 = (float*)(ws + 4 * MB8 + 16777216);

  dim3 blk(256);
  // QKV projections: [4096,1024] = x @ W + b  (bf16 out)
  gemm_kernel<false, true, false><<<dim3(8, 32), blk, 0, stream>>>(x, Wq, bq, Qb, 4096, 1024, 1024);
  gemm_kernel<false, true, false><<<dim3(8, 32), blk, 0, stream>>>(x, Wk, bk, Kb, 4096, 1024, 1024);
  gemm_kernel<false, true, false><<<dim3(8, 32), blk, 0, stream>>>(x, Wv, bv, Vb, 4096, 1024, 1024);
  // banded attention -> ctx (bf16)
  attn_kernel<<<dim3(32, 16, 2), blk, 0, stream>>>(Qb, Kb, Vb, Cb);
  // sa = ctx @ Wo + bo (fp32)
  gemm_kernel<true, false, false><<<dim3(8, 32), blk, 0, stream>>>(Cb, Wo, bo, SA, 4096, 1024, 1024);
  // x1 = LN(sa + x)
  ln_kernel<<<4096, blk, 0, stream>>>(SA, x, g1, be1, X1);
  // h = gelu(x1 @ W1 + b1) (bf16)
  gemm_kernel<false, true, true><<<dim3(32, 32), blk, 0, stream>>>(X1, W1, b1, Hb, 4096, 4096, 1024);
  // y = h @ W2 + b2 (fp32, overlays sa)
  gemm_kernel<true, false, false><<<dim3(8, 32), blk, 0, stream>>>(Hb, W2, b2, SA, 4096, 1024, 4096);
  // out = LN(y + x1)
  ln_kernel<<<4096, blk, 0, stream>>>(SA, X1, g2, be2, (float*)d_out);
}

// Round 2
// 495.275 us; speedup vs baseline: 2.6810x; 2.6810x over previous
//
#include <hip/hip_runtime.h>
#include <cstdint>
#include <math.h>

typedef unsigned short u16;
typedef __attribute__((ext_vector_type(8))) short bf16x8;  // 8 bf16 (4 VGPRs)
typedef __attribute__((ext_vector_type(4))) float f32x4;   // MFMA acc

#define DEVI __device__ __forceinline__

DEVI u16 f2bf(float f) {
  union { float f; uint32_t u; } v; v.f = f;
  return (u16)((v.u + 0x7FFFu + ((v.u >> 16) & 1u)) >> 16);  // RNE
}

// async global->LDS, 16B per lane. LDS dst = wave-uniform base + lane*16.
DEVI void gload16(const void* g, void* l) {
  __builtin_amdgcn_global_load_lds(
      (const __attribute__((address_space(1))) void*)g,
      (__attribute__((address_space(3))) void*)l, 16, 0, 0);
}

// ---------------------------------------------------------------------------
// fp32 -> bf16 plain convert (n multiple of 1024; 4 elems/thread)
// ---------------------------------------------------------------------------
__global__ __launch_bounds__(256)
void cvt_kernel(const float* __restrict__ in, u16* __restrict__ out) {
  int i = (blockIdx.x * 256 + threadIdx.x) * 4;
  float4 f = *(const float4*)(in + i);
  uint32_t lo = (uint32_t)f2bf(f.x) | ((uint32_t)f2bf(f.y) << 16);
  uint32_t hi = (uint32_t)f2bf(f.z) | ((uint32_t)f2bf(f.w) << 16);
  *(uint2*)(out + i) = make_uint2(lo, hi);
}

// ---------------------------------------------------------------------------
// fp32 W[K][N] -> bf16 Wt[N][K] (transpose-convert), 64x64 tiles via LDS
// ---------------------------------------------------------------------------
__global__ __launch_bounds__(256)
void tcvt_kernel(const float* __restrict__ W, u16* __restrict__ Wt, int Kd, int N) {
  __shared__ float t[64 * 68];
  const int n0 = blockIdx.x * 64, k0 = blockIdx.y * 64;
  const int r = threadIdx.x >> 4, c4 = (threadIdx.x & 15) * 4;
#pragma unroll
  for (int p = 0; p < 4; ++p) {
    int row = p * 16 + r;
    float4 f = *(const float4*)(W + (size_t)(k0 + row) * N + n0 + c4);
    *(float4*)&t[row * 68 + c4] = f;
  }
  __syncthreads();
#pragma unroll
  for (int p = 0; p < 4; ++p) {
    int n = p * 16 + r;
    float v0 = t[(c4 + 0) * 68 + n];
    float v1 = t[(c4 + 1) * 68 + n];
    float v2 = t[(c4 + 2) * 68 + n];
    float v3 = t[(c4 + 3) * 68 + n];
    uint32_t lo = (uint32_t)f2bf(v0) | ((uint32_t)f2bf(v1) << 16);
    uint32_t hi = (uint32_t)f2bf(v2) | ((uint32_t)f2bf(v3) << 16);
    *(uint2*)(Wt + (size_t)(n0 + n) * Kd + k0 + c4) = make_uint2(lo, hi);
  }
}

// ---------------------------------------------------------------------------
// GEMM (m97 structure): C[M,N] = act(A[M,K] @ Bt[N,K]^T + bias)
// A,Bt bf16; 128x128 tile, BK=32, 256 thr (4 waves, 64x64 each, 4x4 MFMA).
// Staging via global_load_lds width=16; LDS unpadded [row][k] stride 32 u16.
// ---------------------------------------------------------------------------
template<bool C_BF16, bool GELU_ACT>
__global__ __launch_bounds__(256)
void gemm_kernel(const u16* __restrict__ A, const u16* __restrict__ Bt,
                 const float* __restrict__ bias, void* __restrict__ Cv,
                 int N, int Kd)
{
  __shared__ u16 As[128 * 32];
  __shared__ u16 Bs[128 * 32];
  const int tid = threadIdx.x;
  const int m0 = blockIdx.y * 128;
  const int n0 = blockIdx.x * 128;
  const int w = tid >> 6, lane = tid & 63;
  const int wm = (w >> 1) * 64, wn = (w & 1) * 64;
  const int mr = lane & 15, ko = (lane >> 4) * 8;
  const int w32 = w * 32;

  f32x4 acc[4][4];
#pragma unroll
  for (int i = 0; i < 4; ++i)
#pragma unroll
    for (int j = 0; j < 4; ++j) {
      f32x4 z = {0.f, 0.f, 0.f, 0.f};
      acc[i][j] = z;
    }

  // per-lane global source (16B each, 4 lanes per 32-k row)
  const int lr = lane >> 2, lk = (lane & 3) * 8;
  const u16* aG = A  + (size_t)(m0 + w32 + lr) * Kd + lk;
  const u16* bG = Bt + (size_t)(n0 + w32 + lr) * Kd + lk;
  u16* aL0 = &As[(w32 +  0) * 32];
  u16* aL1 = &As[(w32 + 16) * 32];
  u16* bL0 = &Bs[(w32 +  0) * 32];
  u16* bL1 = &Bs[(w32 + 16) * 32];
  const size_t row16 = (size_t)16 * Kd;

  for (int k0 = 0; k0 < Kd; k0 += 32) {
    gload16(aG + k0,         aL0);
    gload16(aG + row16 + k0, aL1);
    gload16(bG + k0,         bL0);
    gload16(bG + row16 + k0, bL1);
    __syncthreads();
    bf16x8 af[4], bf[4];
#pragma unroll
    for (int i = 0; i < 4; ++i)
      af[i] = *(const bf16x8*)&As[(wm + i * 16 + mr) * 32 + ko];
#pragma unroll
    for (int i = 0; i < 4; ++i)
      bf[i] = *(const bf16x8*)&Bs[(wn + i * 16 + mr) * 32 + ko];
#pragma unroll
    for (int i = 0; i < 4; ++i)
#pragma unroll
      for (int j = 0; j < 4; ++j)
        acc[i][j] = __builtin_amdgcn_mfma_f32_16x16x32_bf16(af[i], bf[j], acc[i][j], 0, 0, 0);
    __syncthreads();
  }

  const int rq = (lane >> 4) * 4;
#pragma unroll
  for (int i = 0; i < 4; ++i) {
    int rbase = m0 + wm + i * 16 + rq;
#pragma unroll
    for (int j = 0; j < 4; ++j) {
      int col = n0 + wn + j * 16 + mr;
      float bv = bias[col];
#pragma unroll
      for (int r = 0; r < 4; ++r) {
        float v = acc[i][j][r] + bv;
        if (GELU_ACT) v = 0.5f * v * (1.f + erff(v * 0.70710678118654752f));
        size_t off = (size_t)(rbase + r) * N + col;
        if (C_BF16) ((u16*)Cv)[off] = f2bf(v);
        else        ((float*)Cv)[off] = v;
      }
    }
  }
}

// ---------------------------------------------------------------------------
// Banded MFMA flash attention: block=(64-q tile, h, b), 256 thr (4 waves).
// Wave w owns q rows w*16..w*16+15. 9 key chunks of 64; band +-256.
// QK^T and PV via mfma 16x16x32 bf16; P round-trips LDS (C-layout->A-layout).
// Scale 1/sqrt(2048) folded into softmax (Q stays raw bf16).
// ---------------------------------------------------------------------------
__global__ __launch_bounds__(256)
void attn_kernel(const u16* __restrict__ Q, const u16* __restrict__ Kx,
                 const u16* __restrict__ V, u16* __restrict__ ctx)
{
  const int KS = 2048, HD = 1024;
  __shared__ u16 Qs[64 * 80];    // [q][d], stride 80 u16 (160B, 16B-aligned)
  __shared__ u16 Ks[64 * 80];    // [t][d]
  __shared__ u16 Vts[64 * 80];   // [d][t] (transposed)
  __shared__ u16 Ps[64 * 88];    // [q][t], stride 88 u16 (176B, 16B-aligned)

  const int qt = blockIdx.x, hh = blockIdx.y, bb = blockIdx.z;
  const int s0 = qt * 64;
  const int tid = threadIdx.x, w = tid >> 6, lane = tid & 63;
  const int quad = lane >> 4, mr = lane & 15;
  const int sr = tid >> 3, sc = (tid & 7) * 8;   // staging: 32 rows x 8-col chunks
  const float qsc = 0.022097086912079608f;       // 1/sqrt(2048)

  // stage Q once
#pragma unroll
  for (int p = 0; p < 2; ++p) {
    int row = p * 32 + sr;
    uint4 u = *(const uint4*)(Q + (size_t)(bb * KS + s0 + row) * HD + hh * 64 + sc);
    *(uint4*)&Qs[row * 80 + sc] = u;
  }

  f32x4 accO[4];
#pragma unroll
  for (int j = 0; j < 4; ++j) { f32x4 z = {0.f,0.f,0.f,0.f}; accO[j] = z; }
  float m_[4] = {-INFINITY, -INFINITY, -INFINITY, -INFINITY};
  float l_[4] = {0.f, 0.f, 0.f, 0.f};

  for (int c = 0; c < 9; ++c) {
    int tb = s0 - 256 + c * 64;
    if (tb < 0 || tb >= KS) continue;            // block-uniform
    __syncthreads();                              // prev chunk's LDS reads done
    // stage K chunk [t][d] and V transposed [d][t]
#pragma unroll
    for (int p = 0; p < 2; ++p) {
      int row = p * 32 + sr;
      uint4 uk = *(const uint4*)(Kx + (size_t)(bb * KS + tb + row) * HD + hh * 64 + sc);
      *(uint4*)&Ks[row * 80 + sc] = uk;
      uint4 uv = *(const uint4*)(V + (size_t)(bb * KS + tb + row) * HD + hh * 64 + sc);
      uint32_t vv[4] = {uv.x, uv.y, uv.z, uv.w};
#pragma unroll
      for (int j = 0; j < 4; ++j) {
        Vts[(sc + 2 * j + 0) * 80 + row] = (u16)(vv[j] & 0xFFFFu);
        Vts[(sc + 2 * j + 1) * 80 + row] = (u16)(vv[j] >> 16);
      }
    }
    __syncthreads();

    // S = Q K^T  (wave computes 16q x 64t)
    f32x4 sacc[4];
#pragma unroll
    for (int j = 0; j < 4; ++j) { f32x4 z = {0.f,0.f,0.f,0.f}; sacc[j] = z; }
#pragma unroll
    for (int s = 0; s < 2; ++s) {
      bf16x8 aq = *(const bf16x8*)&Qs[(w * 16 + mr) * 80 + s * 32 + quad * 8];
#pragma unroll
      for (int j = 0; j < 4; ++j) {
        bf16x8 bk = *(const bf16x8*)&Ks[(j * 16 + mr) * 80 + s * 32 + quad * 8];
        sacc[j] = __builtin_amdgcn_mfma_f32_16x16x32_bf16(aq, bk, sacc[j], 0, 0, 0);
      }
    }

    // online softmax per row r (q = s0 + w*16 + quad*4 + r), reduce over quad
    float alpha[4];
#pragma unroll
    for (int r = 0; r < 4; ++r) {
      int qg = s0 + w * 16 + quad * 4 + r;
      float sv[4], mx = -INFINITY;
#pragma unroll
      for (int j = 0; j < 4; ++j) {
        int tg = tb + j * 16 + mr;
        float s = sacc[j][r] * qsc;
        int d = qg - tg;
        if (d > 256 || d < -256) s = -INFINITY;
        sv[j] = s;
        mx = fmaxf(mx, s);
      }
      mx = fmaxf(mx, __shfl_xor(mx, 1, 64));
      mx = fmaxf(mx, __shfl_xor(mx, 2, 64));
      mx = fmaxf(mx, __shfl_xor(mx, 4, 64));
      mx = fmaxf(mx, __shfl_xor(mx, 8, 64));
      float mn = fmaxf(m_[r], mx);
      float sum = 0.f;
      int prow = (w * 16 + quad * 4 + r) * 88;
#pragma unroll
      for (int j = 0; j < 4; ++j) {
        float p = __expf(sv[j] - mn);
        sum += p;
        Ps[prow + j * 16 + mr] = f2bf(p);
      }
      sum += __shfl_xor(sum, 1, 64);
      sum += __shfl_xor(sum, 2, 64);
      sum += __shfl_xor(sum, 4, 64);
      sum += __shfl_xor(sum, 8, 64);
      alpha[r] = __expf(m_[r] - mn);
      l_[r] = l_[r] * alpha[r] + sum;
      m_[r] = mn;
    }
    // rescale O, then O += P V   (no barrier: wave reads only its own Ps rows)
#pragma unroll
    for (int j = 0; j < 4; ++j)
#pragma unroll
      for (int r = 0; r < 4; ++r) accO[j][r] *= alpha[r];
#pragma unroll
    for (int s = 0; s < 2; ++s) {
      bf16x8 ap = *(const bf16x8*)&Ps[(w * 16 + mr) * 88 + s * 32 + quad * 8];
#pragma unroll
      for (int j = 0; j < 4; ++j) {
        bf16x8 bv = *(const bf16x8*)&Vts[(j * 16 + mr) * 80 + s * 32 + quad * 8];
        accO[j] = __builtin_amdgcn_mfma_f32_16x16x32_bf16(ap, bv, accO[j], 0, 0, 0);
      }
    }
  }

  // epilogue: ctx[q][d] = O/l
#pragma unroll
  for (int r = 0; r < 4; ++r) {
    int qg = s0 + w * 16 + quad * 4 + r;
    float inv = 1.f / l_[r];
#pragma unroll
    for (int j = 0; j < 4; ++j) {
      int d = hh * 64 + j * 16 + mr;
      ctx[(size_t)(bb * KS + qg) * HD + d] = f2bf(accO[j][r] * inv);
    }
  }
}

// ---------------------------------------------------------------------------
// LayerNorm(a + b) over D=1024; fp32 out + optional bf16 out.
// ---------------------------------------------------------------------------
__global__ __launch_bounds__(256)
void ln_kernel(const float* __restrict__ a, const float* __restrict__ b,
               const float* __restrict__ g, const float* __restrict__ be,
               float* __restrict__ out, u16* __restrict__ outb)
{
  __shared__ float red[8];
  const int row = blockIdx.x, tid = threadIdx.x;
  const int w = tid >> 6, lane = tid & 63;
  size_t base = (size_t)row * 1024 + tid * 4;
  float4 va = *(const float4*)(a + base);
  float4 vb = *(const float4*)(b + base);
  float v0 = va.x + vb.x, v1 = va.y + vb.y, v2 = va.z + vb.z, v3 = va.w + vb.w;
  float s1 = v0 + v1 + v2 + v3;
  float s2 = v0 * v0 + v1 * v1 + v2 * v2 + v3 * v3;
#pragma unroll
  for (int o = 32; o > 0; o >>= 1) {
    s1 += __shfl_xor(s1, o, 64);
    s2 += __shfl_xor(s2, o, 64);
  }
  if (lane == 0) { red[w] = s1; red[4 + w] = s2; }
  __syncthreads();
  s1 = red[0] + red[1] + red[2] + red[3];
  s2 = red[4] + red[5] + red[6] + red[7];
  float mu = s1 * (1.f / 1024.f);
  float var = s2 * (1.f / 1024.f) - mu * mu;
  float rs = rsqrtf(var + 1e-5f);
  float4 gv = *(const float4*)(g + tid * 4);
  float4 bv = *(const float4*)(be + tid * 4);
  float4 ov;
  ov.x = (v0 - mu) * rs * gv.x + bv.x;
  ov.y = (v1 - mu) * rs * gv.y + bv.y;
  ov.z = (v2 - mu) * rs * gv.z + bv.z;
  ov.w = (v3 - mu) * rs * gv.w + bv.w;
  *(float4*)(out + base) = ov;
  if (outb) {
    uint32_t lo = (uint32_t)f2bf(ov.x) | ((uint32_t)f2bf(ov.y) << 16);
    uint32_t hi = (uint32_t)f2bf(ov.z) | ((uint32_t)f2bf(ov.w) << 16);
    *(uint2*)(outb + base) = make_uint2(lo, hi);
  }
}

// ---------------------------------------------------------------------------
// ws layout (exactly 64 MiB), MiB offsets:
//  [0,8)   W1T bf16           -> after W1 GEMM: W2T bf16
//  [8,16)  xb bf16            \
//  [16,22) WqT/WkT/WvT        |-> after LN1: Hb bf16 [8,40)
//  [22,24) WoT                |
//  [24,32) Qb  \ after attn:  |
//  [32,40) Kb  / SA fp32 [24,40)
//  [40,48) Vb  \ after Wo+LN1: X1 fp32 [40,56)
//  [48,56) Cb  /
//  [56,64) X1b bf16
//  y fp32 -> d_out directly; LN2 in place on d_out.
// ---------------------------------------------------------------------------
extern "C" void kernel_launch(void* const* d_in, const int* in_sizes, int n_in,
                              void* d_out, int out_size, void* d_ws, size_t ws_size,
                              hipStream_t stream)
{
  (void)in_sizes; (void)n_in; (void)out_size; (void)ws_size;
  const float* x   = (const float*)d_in[0];
  const float* Wq  = (const float*)d_in[1];
  const float* bq  = (const float*)d_in[2];
  const float* Wk  = (const float*)d_in[3];
  const float* bk  = (const float*)d_in[4];
  const float* Wv  = (const float*)d_in[5];
  const float* bv  = (const float*)d_in[6];
  const float* Wo  = (const float*)d_in[7];
  const float* bo  = (const float*)d_in[8];
  const float* W1  = (const float*)d_in[9];
  const float* b1  = (const float*)d_in[10];
  const float* W2  = (const float*)d_in[11];
  const float* b2  = (const float*)d_in[12];
  const float* g1  = (const float*)d_in[13];
  const float* be1 = (const float*)d_in[14];
  const float* g2  = (const float*)d_in[15];
  const float* be2 = (const float*)d_in[16];

  char* ws = (char*)d_ws;
  const size_t MB = 1048576;
  u16* W1T = (u16*)(ws + 0 * MB);
  u16* W2T = (u16*)(ws + 0 * MB);
  u16* xb  = (u16*)(ws + 8 * MB);
  u16* WqT = (u16*)(ws + 16 * MB);
  u16* WkT = (u16*)(ws + 18 * MB);
  u16* WvT = (u16*)(ws + 20 * MB);
  u16* WoT = (u16*)(ws + 22 * MB);
  u16* Qb  = (u16*)(ws + 24 * MB);
  u16* Kb  = (u16*)(ws + 32 * MB);
  u16* Vb  = (u16*)(ws + 40 * MB);
  u16* Cb  = (u16*)(ws + 48 * MB);
  float* SA = (float*)(ws + 24 * MB);
  float* X1 = (float*)(ws + 40 * MB);
  u16* X1b = (u16*)(ws + 56 * MB);
  u16* Hb  = (u16*)(ws + 8 * MB);
  float* yout = (float*)d_out;

  dim3 blk(256);
  // converts
  cvt_kernel<<<4096, blk, 0, stream>>>(x, xb);
  tcvt_kernel<<<dim3(16, 16), blk, 0, stream>>>(Wq, WqT, 1024, 1024);
  tcvt_kernel<<<dim3(16, 16), blk, 0, stream>>>(Wk, WkT, 1024, 1024);
  tcvt_kernel<<<dim3(16, 16), blk, 0, stream>>>(Wv, WvT, 1024, 1024);
  tcvt_kernel<<<dim3(16, 16), blk, 0, stream>>>(Wo, WoT, 1024, 1024);
  tcvt_kernel<<<dim3(64, 16), blk, 0, stream>>>(W1, W1T, 1024, 4096);
  // QKV projections
  gemm_kernel<true, false><<<dim3(8, 32), blk, 0, stream>>>(xb, WqT, bq, Qb, 1024, 1024);
  gemm_kernel<true, false><<<dim3(8, 32), blk, 0, stream>>>(xb, WkT, bk, Kb, 1024, 1024);
  gemm_kernel<true, false><<<dim3(8, 32), blk, 0, stream>>>(xb, WvT, bv, Vb, 1024, 1024);
  // attention
  attn_kernel<<<dim3(32, 16, 2), blk, 0, stream>>>(Qb, Kb, Vb, Cb);
  // sa = ctx @ Wo + bo
  gemm_kernel<false, false><<<dim3(8, 32), blk, 0, stream>>>(Cb, WoT, bo, SA, 1024, 1024);
  // x1 = LN(sa + x)  (fp32 + bf16)
  ln_kernel<<<4096, blk, 0, stream>>>(SA, x, g1, be1, X1, X1b);
  // h = gelu(x1 @ W1 + b1)
  gemm_kernel<true, true><<<dim3(32, 32), blk, 0, stream>>>(X1b, W1T, b1, Hb, 4096, 1024);
  // W2T (overlays dead W1T)
  tcvt_kernel<<<dim3(16, 64), blk, 0, stream>>>(W2, W2T, 4096, 1024);
  // y = h @ W2 + b2 -> d_out
  gemm_kernel<false, false><<<dim3(8, 32), blk, 0, stream>>>(Hb, W2T, b2, yout, 1024, 4096);
  // out = LN(y + x1) in place
  ln_kernel<<<4096, blk, 0, stream>>>(yout, X1, g2, be2, yout, (u16*)nullptr);
}

// Round 3
// 409.021 us; speedup vs baseline: 3.2464x; 1.2109x over previous
//
#include <hip/hip_runtime.h>
#include <cstdint>
#include <math.h>

typedef unsigned short u16;
typedef __attribute__((ext_vector_type(8))) short bf16x8;  // 8 bf16 (4 VGPRs)
typedef __attribute__((ext_vector_type(4))) float f32x4;   // MFMA acc

#define DEVI __device__ __forceinline__

DEVI u16 f2bf(float f) {
  union { float f; uint32_t u; } v; v.f = f;
  return (u16)((v.u + 0x7FFFu + ((v.u >> 16) & 1u)) >> 16);  // RNE
}
DEVI float bf2f(u16 h) {
  union { uint32_t u; float f; } v; v.u = ((uint32_t)h) << 16;
  return v.f;
}

// async global->LDS, 16B per lane. LDS dst = wave-uniform base + lane*16.
DEVI void gload16(const void* g, void* l) {
  __builtin_amdgcn_global_load_lds(
      (const __attribute__((address_space(1))) void*)g,
      (__attribute__((address_space(3))) void*)l, 16, 0, 0);
}

// ---------------------------------------------------------------------------
// fp32 -> bf16 plain convert (4 elems/thread)
// ---------------------------------------------------------------------------
__global__ __launch_bounds__(256)
void cvt_kernel(const float* __restrict__ in, u16* __restrict__ out) {
  int i = (blockIdx.x * 256 + threadIdx.x) * 4;
  float4 f = *(const float4*)(in + i);
  uint32_t lo = (uint32_t)f2bf(f.x) | ((uint32_t)f2bf(f.y) << 16);
  uint32_t hi = (uint32_t)f2bf(f.z) | ((uint32_t)f2bf(f.w) << 16);
  *(uint2*)(out + i) = make_uint2(lo, hi);
}

// ---------------------------------------------------------------------------
// bias concat: out[0..3071] = {bq | bk | bv}
// ---------------------------------------------------------------------------
__global__ __launch_bounds__(256)
void bcat_kernel(const float* __restrict__ bq, const float* __restrict__ bk,
                 const float* __restrict__ bv, float* __restrict__ out) {
  int i = blockIdx.x * 256 + threadIdx.x;  // 0..3071
  const float* s = (i < 1024) ? bq : ((i < 2048) ? bk : bv);
  out[i] = s[i & 1023];
}

// ---------------------------------------------------------------------------
// fp32 W[K][N] -> bf16 Wt[N][K] (transpose-convert), 64x64 tiles via LDS
// ---------------------------------------------------------------------------
__global__ __launch_bounds__(256)
void tcvt_kernel(const float* __restrict__ W, u16* __restrict__ Wt, int Kd, int N) {
  __shared__ float t[64 * 68];
  const int n0 = blockIdx.x * 64, k0 = blockIdx.y * 64;
  const int r = threadIdx.x >> 4, c4 = (threadIdx.x & 15) * 4;
#pragma unroll
  for (int p = 0; p < 4; ++p) {
    int row = p * 16 + r;
    float4 f = *(const float4*)(W + (size_t)(k0 + row) * N + n0 + c4);
    *(float4*)&t[row * 68 + c4] = f;
  }
  __syncthreads();
#pragma unroll
  for (int p = 0; p < 4; ++p) {
    int n = p * 16 + r;
    float v0 = t[(c4 + 0) * 68 + n];
    float v1 = t[(c4 + 1) * 68 + n];
    float v2 = t[(c4 + 2) * 68 + n];
    float v3 = t[(c4 + 3) * 68 + n];
    uint32_t lo = (uint32_t)f2bf(v0) | ((uint32_t)f2bf(v1) << 16);
    uint32_t hi = (uint32_t)f2bf(v2) | ((uint32_t)f2bf(v3) << 16);
    *(uint2*)(Wt + (size_t)(n0 + n) * Kd + k0 + c4) = make_uint2(lo, hi);
  }
}

// ---------------------------------------------------------------------------
// GEMM (m97 structure): C = act(A[M,Kfull] @ Bt[N,Kfull]^T + bias)
// 128x128 tile, BK=32, 256 thr. Staging via global_load_lds width=16.
// MODE 0: bf16 out (+bias).  MODE 1: bf16 out (+bias, GELU).
// MODE 2: split-K over gridDim.z=2; z covers K [z*Kpart,(z+1)*Kpart);
//         z==0 -> fp32 out+bias to C0; z==1 -> bf16 raw partial to C1.
// ---------------------------------------------------------------------------
template<int MODE>
__global__ __launch_bounds__(256)
void gemm_kernel(const u16* __restrict__ A, const u16* __restrict__ Bt,
                 const float* __restrict__ bias, void* __restrict__ C0,
                 void* __restrict__ C1, int N, int Kfull, int Kpart)
{
  __shared__ u16 As[128 * 32];
  __shared__ u16 Bs[128 * 32];
  const int tid = threadIdx.x;
  const int m0 = blockIdx.y * 128;
  const int n0 = blockIdx.x * 128;
  const int kbase = (MODE == 2) ? (int)blockIdx.z * Kpart : 0;
  const int w = tid >> 6, lane = tid & 63;
  const int wm = (w >> 1) * 64, wn = (w & 1) * 64;
  const int mr = lane & 15, ko = (lane >> 4) * 8;
  const int w32 = w * 32;

  f32x4 acc[4][4];
#pragma unroll
  for (int i = 0; i < 4; ++i)
#pragma unroll
    for (int j = 0; j < 4; ++j) {
      f32x4 z = {0.f, 0.f, 0.f, 0.f};
      acc[i][j] = z;
    }

  const int lr = lane >> 2, lk = (lane & 3) * 8;
  const u16* aG = A  + (size_t)(m0 + w32 + lr) * Kfull + kbase + lk;
  const u16* bG = Bt + (size_t)(n0 + w32 + lr) * Kfull + kbase + lk;
  u16* aL0 = &As[(w32 +  0) * 32];
  u16* aL1 = &As[(w32 + 16) * 32];
  u16* bL0 = &Bs[(w32 +  0) * 32];
  u16* bL1 = &Bs[(w32 + 16) * 32];
  const size_t row16 = (size_t)16 * Kfull;

  for (int k0 = 0; k0 < Kpart; k0 += 32) {
    gload16(aG + k0,         aL0);
    gload16(aG + row16 + k0, aL1);
    gload16(bG + k0,         bL0);
    gload16(bG + row16 + k0, bL1);
    __syncthreads();
    bf16x8 af[4], bf[4];
#pragma unroll
    for (int i = 0; i < 4; ++i)
      af[i] = *(const bf16x8*)&As[(wm + i * 16 + mr) * 32 + ko];
#pragma unroll
    for (int i = 0; i < 4; ++i)
      bf[i] = *(const bf16x8*)&Bs[(wn + i * 16 + mr) * 32 + ko];
#pragma unroll
    for (int i = 0; i < 4; ++i)
#pragma unroll
      for (int j = 0; j < 4; ++j)
        acc[i][j] = __builtin_amdgcn_mfma_f32_16x16x32_bf16(af[i], bf[j], acc[i][j], 0, 0, 0);
    __syncthreads();
  }

  const int rq = (lane >> 4) * 4;
  const bool part1 = (MODE == 2) && (blockIdx.z == 1);
#pragma unroll
  for (int i = 0; i < 4; ++i) {
    int rbase = m0 + wm + i * 16 + rq;
#pragma unroll
    for (int j = 0; j < 4; ++j) {
      int col = n0 + wn + j * 16 + mr;
      float bv = part1 ? 0.f : bias[col];
#pragma unroll
      for (int r = 0; r < 4; ++r) {
        float v = acc[i][j][r] + bv;
        if (MODE == 1) v = 0.5f * v * (1.f + erff(v * 0.70710678118654752f));
        size_t off = (size_t)(rbase + r) * N + col;
        if (MODE == 2) {
          if (part1) ((u16*)C1)[off] = f2bf(v);
          else       ((float*)C0)[off] = v;
        } else {
          ((u16*)C0)[off] = f2bf(v);
        }
      }
    }
  }
}

// ---------------------------------------------------------------------------
// Banded MFMA flash attention on fused QKV buffer [4096][3072]
// (cols 0-1023 Q, 1024-2047 K, 2048-3071 V). block=(64-q tile, h, b).
// ---------------------------------------------------------------------------
__global__ __launch_bounds__(256)
void attn_kernel(const u16* __restrict__ QKV, u16* __restrict__ ctx)
{
  const int KS = 2048, QS = 3072, HD = 1024;
  __shared__ u16 Qs[64 * 80];
  __shared__ u16 Ks[64 * 80];
  __shared__ u16 Vts[64 * 80];
  __shared__ u16 Ps[64 * 72];

  const int qt = blockIdx.x, hh = blockIdx.y, bb = blockIdx.z;
  const int s0 = qt * 64;
  const int tid = threadIdx.x, w = tid >> 6, lane = tid & 63;
  const int quad = lane >> 4, mr = lane & 15;
  const int sr = tid >> 3, sc = (tid & 7) * 8;
  const float qsc = 0.022097086912079608f;  // 1/sqrt(2048)

#pragma unroll
  for (int p = 0; p < 2; ++p) {
    int row = p * 32 + sr;
    uint4 u = *(const uint4*)(QKV + (size_t)(bb * KS + s0 + row) * QS + hh * 64 + sc);
    *(uint4*)&Qs[row * 80 + sc] = u;
  }

  f32x4 accO[4];
#pragma unroll
  for (int j = 0; j < 4; ++j) { f32x4 z = {0.f,0.f,0.f,0.f}; accO[j] = z; }
  float m_[4] = {-INFINITY, -INFINITY, -INFINITY, -INFINITY};
  float l_[4] = {0.f, 0.f, 0.f, 0.f};

  for (int c = 0; c < 9; ++c) {
    int tb = s0 - 256 + c * 64;
    if (tb < 0 || tb >= KS) continue;
    __syncthreads();
#pragma unroll
    for (int p = 0; p < 2; ++p) {
      int row = p * 32 + sr;
      uint4 uk = *(const uint4*)(QKV + (size_t)(bb * KS + tb + row) * QS + 1024 + hh * 64 + sc);
      *(uint4*)&Ks[row * 80 + sc] = uk;
      uint4 uv = *(const uint4*)(QKV + (size_t)(bb * KS + tb + row) * QS + 2048 + hh * 64 + sc);
      uint32_t vv[4] = {uv.x, uv.y, uv.z, uv.w};
#pragma unroll
      for (int j = 0; j < 4; ++j) {
        Vts[(sc + 2 * j + 0) * 80 + row] = (u16)(vv[j] & 0xFFFFu);
        Vts[(sc + 2 * j + 1) * 80 + row] = (u16)(vv[j] >> 16);
      }
    }
    __syncthreads();

    f32x4 sacc[4];
#pragma unroll
    for (int j = 0; j < 4; ++j) { f32x4 z = {0.f,0.f,0.f,0.f}; sacc[j] = z; }
#pragma unroll
    for (int s = 0; s < 2; ++s) {
      bf16x8 aq = *(const bf16x8*)&Qs[(w * 16 + mr) * 80 + s * 32 + quad * 8];
#pragma unroll
      for (int j = 0; j < 4; ++j) {
        bf16x8 bk = *(const bf16x8*)&Ks[(j * 16 + mr) * 80 + s * 32 + quad * 8];
        sacc[j] = __builtin_amdgcn_mfma_f32_16x16x32_bf16(aq, bk, sacc[j], 0, 0, 0);
      }
    }

    float alpha[4];
#pragma unroll
    for (int r = 0; r < 4; ++r) {
      int qg = s0 + w * 16 + quad * 4 + r;
      float sv[4], mx = -INFINITY;
#pragma unroll
      for (int j = 0; j < 4; ++j) {
        int tg = tb + j * 16 + mr;
        float s = sacc[j][r] * qsc;
        int d = qg - tg;
        if (d > 256 || d < -256) s = -INFINITY;
        sv[j] = s;
        mx = fmaxf(mx, s);
      }
      mx = fmaxf(mx, __shfl_xor(mx, 1, 64));
      mx = fmaxf(mx, __shfl_xor(mx, 2, 64));
      mx = fmaxf(mx, __shfl_xor(mx, 4, 64));
      mx = fmaxf(mx, __shfl_xor(mx, 8, 64));
      float mn = fmaxf(m_[r], mx);
      float sum = 0.f;
      int prow = (w * 16 + quad * 4 + r) * 72;
#pragma unroll
      for (int j = 0; j < 4; ++j) {
        float p = __expf(sv[j] - mn);
        sum += p;
        Ps[prow + j * 16 + mr] = f2bf(p);
      }
      sum += __shfl_xor(sum, 1, 64);
      sum += __shfl_xor(sum, 2, 64);
      sum += __shfl_xor(sum, 4, 64);
      sum += __shfl_xor(sum, 8, 64);
      alpha[r] = __expf(m_[r] - mn);
      l_[r] = l_[r] * alpha[r] + sum;
      m_[r] = mn;
    }
#pragma unroll
    for (int j = 0; j < 4; ++j)
#pragma unroll
      for (int r = 0; r < 4; ++r) accO[j][r] *= alpha[r];
#pragma unroll
    for (int s = 0; s < 2; ++s) {
      bf16x8 ap = *(const bf16x8*)&Ps[(w * 16 + mr) * 72 + s * 32 + quad * 8];
#pragma unroll
      for (int j = 0; j < 4; ++j) {
        bf16x8 bv = *(const bf16x8*)&Vts[(j * 16 + mr) * 80 + s * 32 + quad * 8];
        accO[j] = __builtin_amdgcn_mfma_f32_16x16x32_bf16(ap, bv, accO[j], 0, 0, 0);
      }
    }
  }

#pragma unroll
  for (int r = 0; r < 4; ++r) {
    int qg = s0 + w * 16 + quad * 4 + r;
    float inv = 1.f / l_[r];
#pragma unroll
    for (int j = 0; j < 4; ++j) {
      int d = hh * 64 + j * 16 + mr;
      ctx[(size_t)(bb * KS + qg) * HD + d] = f2bf(accO[j][r] * inv);
    }
  }
}

// ---------------------------------------------------------------------------
// LayerNorm(a_f32 + a_bf16 + b_f32) over D=1024; fp32 out + optional bf16 out.
// (a_bf16 may be null -> treated as zero.)
// ---------------------------------------------------------------------------
__global__ __launch_bounds__(256)
void ln_kernel(const float* __restrict__ a, const u16* __restrict__ ab,
               const float* __restrict__ b, const float* __restrict__ g,
               const float* __restrict__ be, float* __restrict__ out,
               u16* __restrict__ outb)
{
  __shared__ float red[8];
  const int row = blockIdx.x, tid = threadIdx.x;
  const int w = tid >> 6, lane = tid & 63;
  size_t base = (size_t)row * 1024 + tid * 4;
  float4 va = *(const float4*)(a + base);
  float4 vb = *(const float4*)(b + base);
  float v0 = va.x + vb.x, v1 = va.y + vb.y, v2 = va.z + vb.z, v3 = va.w + vb.w;
  if (ab) {
    uint2 u = *(const uint2*)(ab + base);
    v0 += bf2f((u16)(u.x & 0xFFFFu));
    v1 += bf2f((u16)(u.x >> 16));
    v2 += bf2f((u16)(u.y & 0xFFFFu));
    v3 += bf2f((u16)(u.y >> 16));
  }
  float s1 = v0 + v1 + v2 + v3;
  float s2 = v0 * v0 + v1 * v1 + v2 * v2 + v3 * v3;
#pragma unroll
  for (int o = 32; o > 0; o >>= 1) {
    s1 += __shfl_xor(s1, o, 64);
    s2 += __shfl_xor(s2, o, 64);
  }
  if (lane == 0) { red[w] = s1; red[4 + w] = s2; }
  __syncthreads();
  s1 = red[0] + red[1] + red[2] + red[3];
  s2 = red[4] + red[5] + red[6] + red[7];
  float mu = s1 * (1.f / 1024.f);
  float var = s2 * (1.f / 1024.f) - mu * mu;
  float rs = rsqrtf(var + 1e-5f);
  float4 gv = *(const float4*)(g + tid * 4);
  float4 bv = *(const float4*)(be + tid * 4);
  float4 ov;
  ov.x = (v0 - mu) * rs * gv.x + bv.x;
  ov.y = (v1 - mu) * rs * gv.y + bv.y;
  ov.z = (v2 - mu) * rs * gv.z + bv.z;
  ov.w = (v3 - mu) * rs * gv.w + bv.w;
  *(float4*)(out + base) = ov;
  if (outb) {
    uint32_t lo = (uint32_t)f2bf(ov.x) | ((uint32_t)f2bf(ov.y) << 16);
    uint32_t hi = (uint32_t)f2bf(ov.z) | ((uint32_t)f2bf(ov.w) << 16);
    *(uint2*)(outb + base) = make_uint2(lo, hi);
  }
}

// ---------------------------------------------------------------------------
// ws layout (64 MiB), MiB offsets, timeline-verified:
//  [0,8)   W1T -> W2T (after W1 GEMM)
//  [8,16)  xb  -> X1 fp32 [8,24) (after QKV GEMM / at LN1)
//  [16,22) WqkvT (dead after QKV GEMM)
//  [22,24) WoT   (dead after Wo GEMM)
//  [24,48) QKVb  -> SA0 fp32 [24,40) + SA1 bf16 [40,48) -> Hb bf16 [24,56)
//  [48,56) Cb    -> (part of Hb)
//  [56,64) bqkv (early) -> X1b bf16 -> Y1 bf16
//  Y0 -> d_out; LN2 in place on d_out.
// ---------------------------------------------------------------------------
extern "C" void kernel_launch(void* const* d_in, const int* in_sizes, int n_in,
                              void* d_out, int out_size, void* d_ws, size_t ws_size,
                              hipStream_t stream)
{
  (void)in_sizes; (void)n_in; (void)out_size; (void)ws_size;
  const float* x   = (const float*)d_in[0];
  const float* Wq  = (const float*)d_in[1];
  const float* bq  = (const float*)d_in[2];
  const float* Wk  = (const float*)d_in[3];
  const float* bk  = (const float*)d_in[4];
  const float* Wv  = (const float*)d_in[5];
  const float* bv  = (const float*)d_in[6];
  const float* Wo  = (const float*)d_in[7];
  const float* bo  = (const float*)d_in[8];
  const float* W1  = (const float*)d_in[9];
  const float* b1  = (const float*)d_in[10];
  const float* W2  = (const float*)d_in[11];
  const float* b2  = (const float*)d_in[12];
  const float* g1  = (const float*)d_in[13];
  const float* be1 = (const float*)d_in[14];
  const float* g2  = (const float*)d_in[15];
  const float* be2 = (const float*)d_in[16];

  char* ws = (char*)d_ws;
  const size_t MB = 1048576;
  u16*   W1T   = (u16*)(ws + 0 * MB);
  u16*   W2T   = (u16*)(ws + 0 * MB);
  u16*   xb    = (u16*)(ws + 8 * MB);
  float* X1    = (float*)(ws + 8 * MB);
  u16*   WqkvT = (u16*)(ws + 16 * MB);
  u16*   WoT   = (u16*)(ws + 22 * MB);
  u16*   QKVb  = (u16*)(ws + 24 * MB);
  float* SA0   = (float*)(ws + 24 * MB);
  u16*   SA1   = (u16*)(ws + 40 * MB);
  u16*   Hb    = (u16*)(ws + 24 * MB);
  u16*   Cb    = (u16*)(ws + 48 * MB);
  float* bqkv  = (float*)(ws + 56 * MB);
  u16*   X1b   = (u16*)(ws + 56 * MB);
  u16*   Y1    = (u16*)(ws + 56 * MB);
  float* yout  = (float*)d_out;

  dim3 blk(256);
  // converts + weight prep
  cvt_kernel<<<4096, blk, 0, stream>>>(x, xb);
  tcvt_kernel<<<dim3(16, 16), blk, 0, stream>>>(Wq, WqkvT, 1024, 1024);
  tcvt_kernel<<<dim3(16, 16), blk, 0, stream>>>(Wk, WqkvT + (size_t)1024 * 1024, 1024, 1024);
  tcvt_kernel<<<dim3(16, 16), blk, 0, stream>>>(Wv, WqkvT + (size_t)2048 * 1024, 1024, 1024);
  tcvt_kernel<<<dim3(16, 16), blk, 0, stream>>>(Wo, WoT, 1024, 1024);
  tcvt_kernel<<<dim3(64, 16), blk, 0, stream>>>(W1, W1T, 1024, 4096);
  bcat_kernel<<<12, blk, 0, stream>>>(bq, bk, bv, bqkv);
  // fused QKV projection: [4096,3072], 768 blocks (3/CU)
  gemm_kernel<0><<<dim3(24, 32, 1), blk, 0, stream>>>(xb, WqkvT, bqkv, QKVb, nullptr, 3072, 1024, 1024);
  // banded attention
  attn_kernel<<<dim3(32, 16, 2), blk, 0, stream>>>(QKVb, Cb);
  // sa = ctx @ Wo + bo, split-K=2 (512 blocks)
  gemm_kernel<2><<<dim3(8, 32, 2), blk, 0, stream>>>(Cb, WoT, bo, SA0, SA1, 1024, 1024, 512);
  // x1 = LN(sa0 + sa1 + x)
  ln_kernel<<<4096, blk, 0, stream>>>(SA0, SA1, x, g1, be1, X1, X1b);
  // h = gelu(x1 @ W1 + b1), 1024 blocks (4/CU)
  gemm_kernel<1><<<dim3(32, 32, 1), blk, 0, stream>>>(X1b, W1T, b1, Hb, nullptr, 4096, 1024, 1024);
  // W2T (overlays dead W1T)
  tcvt_kernel<<<dim3(16, 64), blk, 0, stream>>>(W2, W2T, 4096, 1024);
  // y = h @ W2 + b2, split-K=2 (512 blocks): Y0 -> d_out fp32, Y1 bf16
  gemm_kernel<2><<<dim3(8, 32, 2), blk, 0, stream>>>(Hb, W2T, b2, yout, Y1, 1024, 4096, 2048);
  // out = LN(y0 + y1 + x1) in place
  ln_kernel<<<4096, blk, 0, stream>>>(yout, Y1, X1, g2, be2, yout, (u16*)nullptr);
}

// Round 4
// 376.477 us; speedup vs baseline: 3.5270x; 1.0864x over previous
//
#include <hip/hip_runtime.h>
#include <cstdint>
#include <math.h>

typedef unsigned short u16;
typedef __attribute__((ext_vector_type(8))) short bf16x8;  // 8 bf16 (4 VGPRs)
typedef __attribute__((ext_vector_type(4))) float f32x4;   // MFMA acc

#define DEVI __device__ __forceinline__

DEVI u16 f2bf(float f) {
  union { float f; uint32_t u; } v; v.f = f;
  return (u16)((v.u + 0x7FFFu + ((v.u >> 16) & 1u)) >> 16);  // RNE
}
DEVI float bf2f(u16 h) {
  union { uint32_t u; float f; } v; v.u = ((uint32_t)h) << 16;
  return v.f;
}

// async global->LDS, 16B per lane. LDS dst = wave-uniform base + lane*16.
DEVI void gload16(const void* g, void* l) {
  __builtin_amdgcn_global_load_lds(
      (const __attribute__((address_space(1))) void*)g,
      (__attribute__((address_space(3))) void*)l, 16, 0, 0);
}

// tanh-form GELU: u*(1 - 1/(1+e^{2*0.79788456*(u+0.044715u^3)}))
DEVI float gelu_fast(float u) {
  float u2 = u * u;
  float t = __builtin_fmaf(0.044715f * u2, u, u);
  float e = __expf(1.5957691216057308f * t);
  float r = __builtin_amdgcn_rcpf(1.0f + e);
  return u - u * r;
}

// ---------------------------------------------------------------------------
// fp32 -> bf16 plain convert (4 elems/thread)
// ---------------------------------------------------------------------------
__global__ __launch_bounds__(256)
void cvt_kernel(const float* __restrict__ in, u16* __restrict__ out) {
  int i = (blockIdx.x * 256 + threadIdx.x) * 4;
  float4 f = *(const float4*)(in + i);
  uint32_t lo = (uint32_t)f2bf(f.x) | ((uint32_t)f2bf(f.y) << 16);
  uint32_t hi = (uint32_t)f2bf(f.z) | ((uint32_t)f2bf(f.w) << 16);
  *(uint2*)(out + i) = make_uint2(lo, hi);
}

// ---------------------------------------------------------------------------
// bias concat: out[0..3071] = {bq | bk | bv}
// ---------------------------------------------------------------------------
__global__ __launch_bounds__(256)
void bcat_kernel(const float* __restrict__ bq, const float* __restrict__ bk,
                 const float* __restrict__ bv, float* __restrict__ out) {
  int i = blockIdx.x * 256 + threadIdx.x;  // 0..3071
  const float* s = (i < 1024) ? bq : ((i < 2048) ? bk : bv);
  out[i] = s[i & 1023];
}

// ---------------------------------------------------------------------------
// fp32 W[K][N] -> bf16 Wt[N][K] transpose-convert, 64x64 tiles via LDS
// ---------------------------------------------------------------------------
DEVI void tcvt_body(const float* __restrict__ W, u16* __restrict__ Wt,
                    int Kd, int N, int n0, int k0, float* t) {
  const int r = threadIdx.x >> 4, c4 = (threadIdx.x & 15) * 4;
#pragma unroll
  for (int p = 0; p < 4; ++p) {
    int row = p * 16 + r;
    float4 f = *(const float4*)(W + (size_t)(k0 + row) * N + n0 + c4);
    *(float4*)&t[row * 68 + c4] = f;
  }
  __syncthreads();
#pragma unroll
  for (int p = 0; p < 4; ++p) {
    int n = p * 16 + r;
    float v0 = t[(c4 + 0) * 68 + n];
    float v1 = t[(c4 + 1) * 68 + n];
    float v2 = t[(c4 + 2) * 68 + n];
    float v3 = t[(c4 + 3) * 68 + n];
    uint32_t lo = (uint32_t)f2bf(v0) | ((uint32_t)f2bf(v1) << 16);
    uint32_t hi = (uint32_t)f2bf(v2) | ((uint32_t)f2bf(v3) << 16);
    *(uint2*)(Wt + (size_t)(n0 + n) * Kd + k0 + c4) = make_uint2(lo, hi);
  }
}

__global__ __launch_bounds__(256)
void tcvt_kernel(const float* __restrict__ W, u16* __restrict__ Wt, int Kd, int N) {
  __shared__ float t[64 * 68];
  tcvt_body(W, Wt, Kd, N, blockIdx.x * 64, blockIdx.y * 64, t);
}

// 4 square 1024x1024 transposes in one launch (z = Wq,Wk,Wv,Wo)
__global__ __launch_bounds__(256)
void tcvt4_kernel(const float* __restrict__ Wq, const float* __restrict__ Wk,
                  const float* __restrict__ Wv, const float* __restrict__ Wo,
                  u16* __restrict__ WqkvT, u16* __restrict__ WoT) {
  __shared__ float t[64 * 68];
  int z = blockIdx.z;
  const float* W = (z == 0) ? Wq : (z == 1) ? Wk : (z == 2) ? Wv : Wo;
  u16* dst = (z == 3) ? WoT : WqkvT + (size_t)z * 1024 * 1024;
  tcvt_body(W, dst, 1024, 1024, blockIdx.x * 64, blockIdx.y * 64, t);
}

// ---------------------------------------------------------------------------
// GEMM (m97 structure): 128x128 tile, BK=32, 256 thr, global_load_lds w=16.
// MODE 0: fused QKV epilogue — cols<2048 -> QKb[row][col] (stride 2048, bias);
//         cols>=2048 -> Vt[(col-2048)][row] (V transposed, packed 8B stores).
// MODE 1: bf16 out + bias + fast GELU (stride N).
// MODE 2: split-K over gridDim.z=2; z0 -> fp32+bias to C0; z1 -> bf16 to C1.
// ---------------------------------------------------------------------------
template<int MODE>
__global__ __launch_bounds__(256)
void gemm_kernel(const u16* __restrict__ A, const u16* __restrict__ Bt,
                 const float* __restrict__ bias, void* __restrict__ C0,
                 void* __restrict__ C1, int N, int Kfull, int Kpart)
{
  __shared__ u16 As[128 * 32];
  __shared__ u16 Bs[128 * 32];
  const int tid = threadIdx.x;
  const int m0 = blockIdx.y * 128;
  const int n0 = blockIdx.x * 128;
  const int kbase = (MODE == 2) ? (int)blockIdx.z * Kpart : 0;
  const int w = tid >> 6, lane = tid & 63;
  const int wm = (w >> 1) * 64, wn = (w & 1) * 64;
  const int mr = lane & 15, ko = (lane >> 4) * 8;
  const int w32 = w * 32;

  f32x4 acc[4][4];
#pragma unroll
  for (int i = 0; i < 4; ++i)
#pragma unroll
    for (int j = 0; j < 4; ++j) {
      f32x4 z = {0.f, 0.f, 0.f, 0.f};
      acc[i][j] = z;
    }

  const int lr = lane >> 2, lk = (lane & 3) * 8;
  const u16* aG = A  + (size_t)(m0 + w32 + lr) * Kfull + kbase + lk;
  const u16* bG = Bt + (size_t)(n0 + w32 + lr) * Kfull + kbase + lk;
  u16* aL0 = &As[(w32 +  0) * 32];
  u16* aL1 = &As[(w32 + 16) * 32];
  u16* bL0 = &Bs[(w32 +  0) * 32];
  u16* bL1 = &Bs[(w32 + 16) * 32];
  const size_t row16 = (size_t)16 * Kfull;

  for (int k0 = 0; k0 < Kpart; k0 += 32) {
    gload16(aG + k0,         aL0);
    gload16(aG + row16 + k0, aL1);
    gload16(bG + k0,         bL0);
    gload16(bG + row16 + k0, bL1);
    __syncthreads();
    bf16x8 af[4], bf[4];
#pragma unroll
    for (int i = 0; i < 4; ++i)
      af[i] = *(const bf16x8*)&As[(wm + i * 16 + mr) * 32 + ko];
#pragma unroll
    for (int i = 0; i < 4; ++i)
      bf[i] = *(const bf16x8*)&Bs[(wn + i * 16 + mr) * 32 + ko];
#pragma unroll
    for (int i = 0; i < 4; ++i)
#pragma unroll
      for (int j = 0; j < 4; ++j)
        acc[i][j] = __builtin_amdgcn_mfma_f32_16x16x32_bf16(af[i], bf[j], acc[i][j], 0, 0, 0);
    __syncthreads();
  }

  const int rq = (lane >> 4) * 4;
  if (MODE == 0) {
    if (n0 < 2048) {  // Q,K part -> QKb [4096][2048]
#pragma unroll
      for (int i = 0; i < 4; ++i) {
        int rbase = m0 + wm + i * 16 + rq;
#pragma unroll
        for (int j = 0; j < 4; ++j) {
          int col = n0 + wn + j * 16 + mr;
          float bv = bias[col];
#pragma unroll
          for (int r = 0; r < 4; ++r)
            ((u16*)C0)[(size_t)(rbase + r) * 2048 + col] = f2bf(acc[i][j][r] + bv);
        }
      }
    } else {          // V part -> Vt [1024][4096] (transposed, 8B packed)
#pragma unroll
      for (int i = 0; i < 4; ++i) {
        int rbase = m0 + wm + i * 16 + rq;
#pragma unroll
        for (int j = 0; j < 4; ++j) {
          int col = n0 + wn + j * 16 + mr;
          float bv = bias[col];
          int d = col - 2048;
          uint32_t lo = (uint32_t)f2bf(acc[i][j][0] + bv) |
                        ((uint32_t)f2bf(acc[i][j][1] + bv) << 16);
          uint32_t hi = (uint32_t)f2bf(acc[i][j][2] + bv) |
                        ((uint32_t)f2bf(acc[i][j][3] + bv) << 16);
          *(uint2*)((u16*)C1 + (size_t)d * 4096 + rbase) = make_uint2(lo, hi);
        }
      }
    }
  } else {
    const bool part1 = (MODE == 2) && (blockIdx.z == 1);
#pragma unroll
    for (int i = 0; i < 4; ++i) {
      int rbase = m0 + wm + i * 16 + rq;
#pragma unroll
      for (int j = 0; j < 4; ++j) {
        int col = n0 + wn + j * 16 + mr;
        float bv = part1 ? 0.f : bias[col];
#pragma unroll
        for (int r = 0; r < 4; ++r) {
          float v = acc[i][j][r] + bv;
          if (MODE == 1) v = gelu_fast(v);
          size_t off = (size_t)(rbase + r) * N + col;
          if (MODE == 2) {
            if (part1) ((u16*)C1)[off] = f2bf(v);
            else       ((float*)C0)[off] = v;
          } else {
            ((u16*)C0)[off] = f2bf(v);
          }
        }
      }
    }
  }
}

// ---------------------------------------------------------------------------
// Banded MFMA flash attention, simplified softmax (scores bounded: no online
// max, p = expf(s), single end reduction of l). QKb [4096][2048] (Q|K),
// Vt [1024][4096] pre-transposed. block=(64-q tile, h, b), 256 thr (4 waves).
// ---------------------------------------------------------------------------
__global__ __launch_bounds__(256)
void attn_kernel(const u16* __restrict__ QKb, const u16* __restrict__ Vt,
                 u16* __restrict__ ctx)
{
  const int KS = 2048, HD = 1024;
  __shared__ u16 Qs[64 * 80];
  __shared__ u16 Ks[64 * 80];
  __shared__ u16 Vts[64 * 72];   // [d][t]
  __shared__ u16 Ps[64 * 72];    // [q][t]

  const int qt = blockIdx.x, hh = blockIdx.y, bb = blockIdx.z;
  const int s0 = qt * 64;
  const int tid = threadIdx.x, w = tid >> 6, lane = tid & 63;
  const int quad = lane >> 4, mr = lane & 15;
  const int sr = tid >> 3, sc = (tid & 7) * 8;
  const int vrow = tid >> 2, vtc = (tid & 3) * 16;
  const float qsc = 0.022097086912079608f;  // 1/sqrt(2048)

#pragma unroll
  for (int p = 0; p < 2; ++p) {
    int row = p * 32 + sr;
    uint4 u = *(const uint4*)(QKb + (size_t)(bb * KS + s0 + row) * 2048 + hh * 64 + sc);
    *(uint4*)&Qs[row * 80 + sc] = u;
  }

  f32x4 accO[4];
#pragma unroll
  for (int j = 0; j < 4; ++j) { f32x4 z = {0.f,0.f,0.f,0.f}; accO[j] = z; }
  float lsum[4] = {0.f, 0.f, 0.f, 0.f};

  for (int c = 0; c < 9; ++c) {
    int tb = s0 - 256 + c * 64;
    if (tb < 0 || tb >= KS) continue;
    __syncthreads();
#pragma unroll
    for (int p = 0; p < 2; ++p) {
      int row = p * 32 + sr;
      uint4 uk = *(const uint4*)(QKb + (size_t)(bb * KS + tb + row) * 2048 + 1024 + hh * 64 + sc);
      *(uint4*)&Ks[row * 80 + sc] = uk;
    }
    {
      const u16* vsrc = Vt + (size_t)(hh * 64 + vrow) * 4096 + bb * KS + tb + vtc;
      *(uint4*)&Vts[vrow * 72 + vtc]     = *(const uint4*)vsrc;
      *(uint4*)&Vts[vrow * 72 + vtc + 8] = *(const uint4*)(vsrc + 8);
    }
    __syncthreads();

    f32x4 sacc[4];
#pragma unroll
    for (int j = 0; j < 4; ++j) { f32x4 z = {0.f,0.f,0.f,0.f}; sacc[j] = z; }
#pragma unroll
    for (int s = 0; s < 2; ++s) {
      bf16x8 aq = *(const bf16x8*)&Qs[(w * 16 + mr) * 80 + s * 32 + quad * 8];
#pragma unroll
      for (int j = 0; j < 4; ++j) {
        bf16x8 bk = *(const bf16x8*)&Ks[(j * 16 + mr) * 80 + s * 32 + quad * 8];
        sacc[j] = __builtin_amdgcn_mfma_f32_16x16x32_bf16(aq, bk, sacc[j], 0, 0, 0);
      }
    }

    // p = expf(s) directly (s bounded ~|1.5|; band-masked -> 0)
#pragma unroll
    for (int r = 0; r < 4; ++r) {
      int qg = s0 + w * 16 + quad * 4 + r;
      int prow = (w * 16 + quad * 4 + r) * 72;
      float ls = 0.f;
#pragma unroll
      for (int j = 0; j < 4; ++j) {
        int tg = tb + j * 16 + mr;
        float s = sacc[j][r] * qsc;
        int d = qg - tg;
        if (d > 256 || d < -256) s = -INFINITY;
        float p = __expf(s);
        ls += p;
        Ps[prow + j * 16 + mr] = f2bf(p);
      }
      lsum[r] += ls;
    }
    // PV (wave reads only its own Ps rows; compiler inserts lgkmcnt wait)
#pragma unroll
    for (int s = 0; s < 2; ++s) {
      bf16x8 ap = *(const bf16x8*)&Ps[(w * 16 + mr) * 72 + s * 32 + quad * 8];
#pragma unroll
      for (int j = 0; j < 4; ++j) {
        bf16x8 bv = *(const bf16x8*)&Vts[(j * 16 + mr) * 72 + s * 32 + quad * 8];
        accO[j] = __builtin_amdgcn_mfma_f32_16x16x32_bf16(ap, bv, accO[j], 0, 0, 0);
      }
    }
  }

#pragma unroll
  for (int r = 0; r < 4; ++r) {
    float l = lsum[r];
    l += __shfl_xor(l, 1, 64);
    l += __shfl_xor(l, 2, 64);
    l += __shfl_xor(l, 4, 64);
    l += __shfl_xor(l, 8, 64);
    int qg = s0 + w * 16 + quad * 4 + r;
    float inv = 1.f / l;
#pragma unroll
    for (int j = 0; j < 4; ++j) {
      int d = hh * 64 + j * 16 + mr;
      ctx[(size_t)(bb * KS + qg) * HD + d] = f2bf(accO[j][r] * inv);
    }
  }
}

// ---------------------------------------------------------------------------
// LayerNorm(a_f32 + ab_bf16 + res) over D=1024.
// V=0: res fp32, out bf16 (LN1).  V=1: res bf16, out fp32 (LN2).
// ---------------------------------------------------------------------------
template<int V>
__global__ __launch_bounds__(256)
void ln_kernel(const float* __restrict__ a, const u16* __restrict__ ab,
               const void* __restrict__ res, const float* __restrict__ g,
               const float* __restrict__ be, void* __restrict__ out)
{
  __shared__ float red[8];
  const int row = blockIdx.x, tid = threadIdx.x;
  const int w = tid >> 6, lane = tid & 63;
  size_t base = (size_t)row * 1024 + tid * 4;
  float4 va = *(const float4*)(a + base);
  float v0 = va.x, v1 = va.y, v2 = va.z, v3 = va.w;
  {
    uint2 u = *(const uint2*)(ab + base);
    v0 += bf2f((u16)(u.x & 0xFFFFu));
    v1 += bf2f((u16)(u.x >> 16));
    v2 += bf2f((u16)(u.y & 0xFFFFu));
    v3 += bf2f((u16)(u.y >> 16));
  }
  if (V == 0) {
    float4 vb = *(const float4*)((const float*)res + base);
    v0 += vb.x; v1 += vb.y; v2 += vb.z; v3 += vb.w;
  } else {
    uint2 u = *(const uint2*)((const u16*)res + base);
    v0 += bf2f((u16)(u.x & 0xFFFFu));
    v1 += bf2f((u16)(u.x >> 16));
    v2 += bf2f((u16)(u.y & 0xFFFFu));
    v3 += bf2f((u16)(u.y >> 16));
  }
  float s1 = v0 + v1 + v2 + v3;
  float s2 = v0 * v0 + v1 * v1 + v2 * v2 + v3 * v3;
#pragma unroll
  for (int o = 32; o > 0; o >>= 1) {
    s1 += __shfl_xor(s1, o, 64);
    s2 += __shfl_xor(s2, o, 64);
  }
  if (lane == 0) { red[w] = s1; red[4 + w] = s2; }
  __syncthreads();
  s1 = red[0] + red[1] + red[2] + red[3];
  s2 = red[4] + red[5] + red[6] + red[7];
  float mu = s1 * (1.f / 1024.f);
  float var = s2 * (1.f / 1024.f) - mu * mu;
  float rs = rsqrtf(var + 1e-5f);
  float4 gv = *(const float4*)(g + tid * 4);
  float4 bv = *(const float4*)(be + tid * 4);
  float o0 = (v0 - mu) * rs * gv.x + bv.x;
  float o1 = (v1 - mu) * rs * gv.y + bv.y;
  float o2 = (v2 - mu) * rs * gv.z + bv.z;
  float o3 = (v3 - mu) * rs * gv.w + bv.w;
  if (V == 0) {
    uint32_t lo = (uint32_t)f2bf(o0) | ((uint32_t)f2bf(o1) << 16);
    uint32_t hi = (uint32_t)f2bf(o2) | ((uint32_t)f2bf(o3) << 16);
    *(uint2*)((u16*)out + base) = make_uint2(lo, hi);
  } else {
    float4 ov; ov.x = o0; ov.y = o1; ov.z = o2; ov.w = o3;
    *(float4*)((float*)out + base) = ov;
  }
}

// ---------------------------------------------------------------------------
// ws layout (64 MiB), MiB offsets, lifetime-verified:
//  [0,8)   W1T (prep->G3)        -> Y1 bf16 (G4->LN2)
//  [8,16)  xb (prep->G1)         -> X1b bf16 (LN1->LN2)
//  [16,22) WqkvT (prep->G1)
//  [22,24) WoT (prep->G2)
//  [24,40) QKb (G1->attn)        -> SA0 fp32 (G2->LN1)  -> Hb[lo] (G3->G4)
//  [40,48) Vt  (G1->attn)        -> SA1 bf16 (G2->LN1)  -> Hb[mid]
//  [48,56) bqkv (prep->G1)       -> Cb (attn->G2)       -> Hb[hi]
//  [56,64) W2T (prep->G4)
// ---------------------------------------------------------------------------
extern "C" void kernel_launch(void* const* d_in, const int* in_sizes, int n_in,
                              void* d_out, int out_size, void* d_ws, size_t ws_size,
                              hipStream_t stream)
{
  (void)in_sizes; (void)n_in; (void)out_size; (void)ws_size;
  const float* x   = (const float*)d_in[0];
  const float* Wq  = (const float*)d_in[1];
  const float* bq  = (const float*)d_in[2];
  const float* Wk  = (const float*)d_in[3];
  const float* bk  = (const float*)d_in[4];
  const float* Wv  = (const float*)d_in[5];
  const float* bv  = (const float*)d_in[6];
  const float* Wo  = (const float*)d_in[7];
  const float* bo  = (const float*)d_in[8];
  const float* W1  = (const float*)d_in[9];
  const float* b1  = (const float*)d_in[10];
  const float* W2  = (const float*)d_in[11];
  const float* b2  = (const float*)d_in[12];
  const float* g1  = (const float*)d_in[13];
  const float* be1 = (const float*)d_in[14];
  const float* g2  = (const float*)d_in[15];
  const float* be2 = (const float*)d_in[16];

  char* ws = (char*)d_ws;
  const size_t MB = 1048576;
  u16*   W1T   = (u16*)(ws + 0 * MB);
  u16*   Y1    = (u16*)(ws + 0 * MB);
  u16*   xb    = (u16*)(ws + 8 * MB);
  u16*   X1b   = (u16*)(ws + 8 * MB);
  u16*   WqkvT = (u16*)(ws + 16 * MB);
  u16*   WoT   = (u16*)(ws + 22 * MB);
  u16*   QKb   = (u16*)(ws + 24 * MB);
  float* SA0   = (float*)(ws + 24 * MB);
  u16*   Hb    = (u16*)(ws + 24 * MB);
  u16*   Vt    = (u16*)(ws + 40 * MB);
  u16*   SA1   = (u16*)(ws + 40 * MB);
  float* bqkv  = (float*)(ws + 48 * MB);
  u16*   Cb    = (u16*)(ws + 48 * MB);
  u16*   W2T   = (u16*)(ws + 56 * MB);
  float* yout  = (float*)d_out;

  dim3 blk(256);
  // prep (all upfront, off the GEMM critical path)
  cvt_kernel<<<4096, blk, 0, stream>>>(x, xb);
  tcvt4_kernel<<<dim3(16, 16, 4), blk, 0, stream>>>(Wq, Wk, Wv, Wo, WqkvT, WoT);
  tcvt_kernel<<<dim3(64, 16), blk, 0, stream>>>(W1, W1T, 1024, 4096);
  tcvt_kernel<<<dim3(16, 64), blk, 0, stream>>>(W2, W2T, 4096, 1024);
  bcat_kernel<<<12, blk, 0, stream>>>(bq, bk, bv, bqkv);
  // G1: fused QKV projection (Q,K -> QKb; V -> Vt transposed)
  gemm_kernel<0><<<dim3(24, 32, 1), blk, 0, stream>>>(xb, WqkvT, bqkv, QKb, Vt, 3072, 1024, 1024);
  // attention
  attn_kernel<<<dim3(32, 16, 2), blk, 0, stream>>>(QKb, Vt, Cb);
  // G2: sa = ctx @ Wo + bo, split-K=2
  gemm_kernel<2><<<dim3(8, 32, 2), blk, 0, stream>>>(Cb, WoT, bo, SA0, SA1, 1024, 1024, 512);
  // LN1: x1 = LN(sa0 + sa1 + x) -> bf16
  ln_kernel<0><<<4096, blk, 0, stream>>>(SA0, SA1, x, g1, be1, X1b);
  // G3: h = gelu(x1 @ W1 + b1)
  gemm_kernel<1><<<dim3(32, 32, 1), blk, 0, stream>>>(X1b, W1T, b1, Hb, nullptr, 4096, 1024, 1024);
  // G4: y = h @ W2 + b2, split-K=2 -> d_out fp32 + Y1 bf16
  gemm_kernel<2><<<dim3(8, 32, 2), blk, 0, stream>>>(Hb, W2T, b2, yout, Y1, 1024, 4096, 2048);
  // LN2: out = LN(y0 + y1 + x1) in place
  ln_kernel<1><<<4096, blk, 0, stream>>>(yout, Y1, X1b, g2, be2, yout);
}

// Round 5
// 327.368 us; speedup vs baseline: 4.0561x; 1.1500x over previous
//
#include <hip/hip_runtime.h>
#include <cstdint>
#include <math.h>

typedef unsigned short u16;
typedef __attribute__((ext_vector_type(8))) short bf16x8;  // 8 bf16 (4 VGPRs)
typedef __attribute__((ext_vector_type(4))) float f32x4;   // MFMA acc

#define DEVI __device__ __forceinline__

DEVI u16 f2bf(float f) {
  union { float f; uint32_t u; } v; v.f = f;
  return (u16)((v.u + 0x7FFFu + ((v.u >> 16) & 1u)) >> 16);  // RNE
}
DEVI float bf2f(u16 h) {
  union { uint32_t u; float f; } v; v.u = ((uint32_t)h) << 16;
  return v.f;
}

// async global->LDS, 16B per lane. LDS dst = wave-uniform base + lane*16.
DEVI void gload16(const void* g, void* l) {
  __builtin_amdgcn_global_load_lds(
      (const __attribute__((address_space(1))) void*)g,
      (__attribute__((address_space(3))) void*)l, 16, 0, 0);
}

// tanh-form GELU: u*(1 - 1/(1+e^{2*0.79788456*(u+0.044715u^3)}))
DEVI float gelu_fast(float u) {
  float u2 = u * u;
  float t = __builtin_fmaf(0.044715f * u2, u, u);
  float e = __expf(1.5957691216057308f * t);
  float r = __builtin_amdgcn_rcpf(1.0f + e);
  return u - u * r;
}

// ---------------------------------------------------------------------------
// fp32 W[K][N] -> bf16 Wt[N][K] transpose-convert, one 64x64 tile via LDS
// ---------------------------------------------------------------------------
DEVI void tcvt_body(const float* __restrict__ W, u16* __restrict__ Wt,
                    int Kd, int N, int n0, int k0, float* t) {
  const int r = threadIdx.x >> 4, c4 = (threadIdx.x & 15) * 4;
#pragma unroll
  for (int p = 0; p < 4; ++p) {
    int row = p * 16 + r;
    float4 f = *(const float4*)(W + (size_t)(k0 + row) * N + n0 + c4);
    *(float4*)&t[row * 68 + c4] = f;
  }
  __syncthreads();
#pragma unroll
  for (int p = 0; p < 4; ++p) {
    int n = p * 16 + r;
    float v0 = t[(c4 + 0) * 68 + n];
    float v1 = t[(c4 + 1) * 68 + n];
    float v2 = t[(c4 + 2) * 68 + n];
    float v3 = t[(c4 + 3) * 68 + n];
    uint32_t lo = (uint32_t)f2bf(v0) | ((uint32_t)f2bf(v1) << 16);
    uint32_t hi = (uint32_t)f2bf(v2) | ((uint32_t)f2bf(v3) << 16);
    *(uint2*)(Wt + (size_t)(n0 + n) * Kd + k0 + c4) = make_uint2(lo, hi);
  }
}

// ---------------------------------------------------------------------------
// Fused prep: all weight transpose-converts + x convert + bias concat.
// grid.x = 7180: [0,1024) Wq/Wk/Wv/Wo; [1024,2048) W1; [2048,3072) W2;
// [3072,7168) x cvt; [7168,7180) bias concat.
// ---------------------------------------------------------------------------
__global__ __launch_bounds__(256)
void prep_kernel(const float* __restrict__ Wq, const float* __restrict__ Wk,
                 const float* __restrict__ Wv, const float* __restrict__ Wo,
                 const float* __restrict__ W1, const float* __restrict__ W2,
                 const float* __restrict__ x, const float* __restrict__ bq,
                 const float* __restrict__ bk, const float* __restrict__ bv,
                 u16* __restrict__ WqkvT, u16* __restrict__ WoT,
                 u16* __restrict__ W1T, u16* __restrict__ W2T,
                 u16* __restrict__ xb, float* __restrict__ bqkv)
{
  __shared__ float t[64 * 68];
  const int b = blockIdx.x;
  if (b < 1024) {
    int wsel = b >> 8, tt = b & 255;
    const float* W = (wsel == 0) ? Wq : (wsel == 1) ? Wk : (wsel == 2) ? Wv : Wo;
    u16* dst = (wsel == 3) ? WoT : WqkvT + (size_t)wsel * 1024 * 1024;
    tcvt_body(W, dst, 1024, 1024, (tt & 15) * 64, (tt >> 4) * 64, t);
  } else if (b < 2048) {
    int tt = b - 1024;
    tcvt_body(W1, W1T, 1024, 4096, (tt & 63) * 64, (tt >> 6) * 64, t);
  } else if (b < 3072) {
    int tt = b - 2048;
    tcvt_body(W2, W2T, 4096, 1024, (tt & 15) * 64, (tt >> 4) * 64, t);
  } else if (b < 7168) {
    int i = ((b - 3072) * 256 + threadIdx.x) * 4;
    float4 f = *(const float4*)(x + i);
    uint32_t lo = (uint32_t)f2bf(f.x) | ((uint32_t)f2bf(f.y) << 16);
    uint32_t hi = (uint32_t)f2bf(f.z) | ((uint32_t)f2bf(f.w) << 16);
    *(uint2*)(xb + i) = make_uint2(lo, hi);
  } else {
    int i = (b - 7168) * 256 + threadIdx.x;  // 0..3071
    const float* s = (i < 1024) ? bq : ((i < 2048) ? bk : bv);
    bqkv[i] = s[i & 1023];
  }
}

// ---------------------------------------------------------------------------
// GEMM: 128x128 tile, BK=64 (two stride-32 half-buffers so global_load_lds
// stays legal and LDS reads stay 2-way-conflict-free), 256 thr (4 waves).
// MFMA called with SWAPPED operands: acc[i][j] = D[n][m] — lane holds 4
// CONSECUTIVE n for fixed m -> packed uint2/float4 epilogue stores.
//   m_global = m0 + wm + i*16 + (lane&15)
//   n_global = n0 + wn + j*16 + (lane>>4)*4 + r
// MODE 0: fused QKV — n0<2048 -> QKb[m][n] (stride 2048, bias, uint2);
//         n0>=2048 -> Vt[n-2048][m] (scalar, transposed).
// MODE 1: bf16 out + bias + fast GELU (stride N, uint2).
// MODE 2: split-K gridDim.z=2; z0 -> fp32+bias float4 to C0; z1 -> bf16 uint2 to C1.
// L2 supertile swizzle: GROUP=8 m-tiles per band.
// ---------------------------------------------------------------------------
template<int MODE>
__global__ __launch_bounds__(256, 4)
void gemm_kernel(const u16* __restrict__ A, const u16* __restrict__ Bt,
                 const float* __restrict__ bias, void* __restrict__ C0,
                 void* __restrict__ C1, int N, int Kfull, int Kpart)
{
  __shared__ u16 As0[128 * 32], As1[128 * 32];
  __shared__ u16 Bs0[128 * 32], Bs1[128 * 32];
  const int tid = threadIdx.x;
  // supertile swizzle (8 m-tiles per band)
  const int nbx = gridDim.x, nby = gridDim.y;
  int lin = blockIdx.y * nbx + blockIdx.x;
  int band = lin / (8 * nbx);
  int rem = lin - band * (8 * nbx);
  int gsz = min(nby - band * 8, 8);
  const int m0 = (band * 8 + rem % gsz) * 128;
  const int n0 = (rem / gsz) * 128;
  const int kbase = (MODE == 2) ? (int)blockIdx.z * Kpart : 0;
  const int w = tid >> 6, lane = tid & 63;
  const int wm = (w >> 1) * 64, wn = (w & 1) * 64;
  const int mr = lane & 15, ko = (lane >> 4) * 8;
  const int rq = (lane >> 4) * 4;
  const int w32 = w * 32;

  f32x4 acc[4][4];
#pragma unroll
  for (int i = 0; i < 4; ++i)
#pragma unroll
    for (int j = 0; j < 4; ++j) {
      f32x4 z = {0.f, 0.f, 0.f, 0.f};
      acc[i][j] = z;
    }

  // staging: per gload16, 64 lanes cover 16 rows x 32 k (u16)
  const int lr = lane >> 2, lk = (lane & 3) * 8;
  const u16* aG = A  + (size_t)(m0 + w32 + lr) * Kfull + kbase + lk;
  const u16* bG = Bt + (size_t)(n0 + w32 + lr) * Kfull + kbase + lk;
  u16* aD00 = &As0[(w32 +  0) * 32];
  u16* aD01 = &As0[(w32 + 16) * 32];
  u16* aD10 = &As1[(w32 +  0) * 32];
  u16* aD11 = &As1[(w32 + 16) * 32];
  u16* bD00 = &Bs0[(w32 +  0) * 32];
  u16* bD01 = &Bs0[(w32 + 16) * 32];
  u16* bD10 = &Bs1[(w32 +  0) * 32];
  u16* bD11 = &Bs1[(w32 + 16) * 32];
  const size_t row16 = (size_t)16 * Kfull;

  for (int k0 = 0; k0 < Kpart; k0 += 64) {
    gload16(aG + k0,              aD00);
    gload16(aG + row16 + k0,      aD01);
    gload16(aG + k0 + 32,         aD10);
    gload16(aG + row16 + k0 + 32, aD11);
    gload16(bG + k0,              bD00);
    gload16(bG + row16 + k0,      bD01);
    gload16(bG + k0 + 32,         bD10);
    gload16(bG + row16 + k0 + 32, bD11);
    __syncthreads();
#pragma unroll
    for (int s = 0; s < 2; ++s) {
      const u16* Ap = s ? As1 : As0;
      const u16* Bp = s ? Bs1 : Bs0;
      bf16x8 af[4], bf[4];
#pragma unroll
      for (int i = 0; i < 4; ++i)
        af[i] = *(const bf16x8*)&Ap[(wm + i * 16 + mr) * 32 + ko];
#pragma unroll
      for (int j = 0; j < 4; ++j)
        bf[j] = *(const bf16x8*)&Bp[(wn + j * 16 + mr) * 32 + ko];
#pragma unroll
      for (int i = 0; i < 4; ++i)
#pragma unroll
        for (int j = 0; j < 4; ++j)
          acc[i][j] = __builtin_amdgcn_mfma_f32_16x16x32_bf16(bf[j], af[i], acc[i][j], 0, 0, 0);
    }
    __syncthreads();
  }

  if (MODE == 0) {
    if (n0 < 2048) {  // Q,K -> QKb [4096][2048]
#pragma unroll
      for (int i = 0; i < 4; ++i) {
        size_t mrow = (size_t)(m0 + wm + i * 16 + mr) * 2048;
#pragma unroll
        for (int j = 0; j < 4; ++j) {
          int nb = n0 + wn + j * 16 + rq;
          float4 b4 = *(const float4*)&bias[nb];
          uint32_t lo = (uint32_t)f2bf(acc[i][j][0] + b4.x) |
                        ((uint32_t)f2bf(acc[i][j][1] + b4.y) << 16);
          uint32_t hi = (uint32_t)f2bf(acc[i][j][2] + b4.z) |
                        ((uint32_t)f2bf(acc[i][j][3] + b4.w) << 16);
          *(uint2*)((u16*)C0 + mrow + nb) = make_uint2(lo, hi);
        }
      }
    } else {          // V -> Vt [1024][4096] transposed
#pragma unroll
      for (int i = 0; i < 4; ++i) {
        int mg = m0 + wm + i * 16 + mr;
#pragma unroll
        for (int j = 0; j < 4; ++j) {
          int nb = n0 + wn + j * 16 + rq;
          float4 b4 = *(const float4*)&bias[nb];
          int d = nb - 2048;
          ((u16*)C1)[(size_t)(d + 0) * 4096 + mg] = f2bf(acc[i][j][0] + b4.x);
          ((u16*)C1)[(size_t)(d + 1) * 4096 + mg] = f2bf(acc[i][j][1] + b4.y);
          ((u16*)C1)[(size_t)(d + 2) * 4096 + mg] = f2bf(acc[i][j][2] + b4.z);
          ((u16*)C1)[(size_t)(d + 3) * 4096 + mg] = f2bf(acc[i][j][3] + b4.w);
        }
      }
    }
  } else {
    const bool part1 = (MODE == 2) && (blockIdx.z == 1);
#pragma unroll
    for (int i = 0; i < 4; ++i) {
      size_t mrow = (size_t)(m0 + wm + i * 16 + mr) * N;
#pragma unroll
      for (int j = 0; j < 4; ++j) {
        int nb = n0 + wn + j * 16 + rq;
        if (MODE == 1) {
          float4 b4 = *(const float4*)&bias[nb];
          float v0 = gelu_fast(acc[i][j][0] + b4.x);
          float v1 = gelu_fast(acc[i][j][1] + b4.y);
          float v2 = gelu_fast(acc[i][j][2] + b4.z);
          float v3 = gelu_fast(acc[i][j][3] + b4.w);
          uint32_t lo = (uint32_t)f2bf(v0) | ((uint32_t)f2bf(v1) << 16);
          uint32_t hi = (uint32_t)f2bf(v2) | ((uint32_t)f2bf(v3) << 16);
          *(uint2*)((u16*)C0 + mrow + nb) = make_uint2(lo, hi);
        } else if (part1) {
          uint32_t lo = (uint32_t)f2bf(acc[i][j][0]) | ((uint32_t)f2bf(acc[i][j][1]) << 16);
          uint32_t hi = (uint32_t)f2bf(acc[i][j][2]) | ((uint32_t)f2bf(acc[i][j][3]) << 16);
          *(uint2*)((u16*)C1 + mrow + nb) = make_uint2(lo, hi);
        } else {
          float4 b4 = *(const float4*)&bias[nb];
          float4 ov;
          ov.x = acc[i][j][0] + b4.x;
          ov.y = acc[i][j][1] + b4.y;
          ov.z = acc[i][j][2] + b4.z;
          ov.w = acc[i][j][3] + b4.w;
          *(float4*)((float*)C0 + mrow + nb) = ov;
        }
      }
    }
  }
}

// ---------------------------------------------------------------------------
// Banded MFMA flash attention, simplified softmax. QK^T computed with swapped
// operands -> S[t][q]: lane owns ONE q (=mr) -> packed b64 P-writes, scalar l.
// PV also swapped -> O[d][q]: packed uint2 ctx stores, l already per-lane.
// ---------------------------------------------------------------------------
__global__ __launch_bounds__(256)
void attn_kernel(const u16* __restrict__ QKb, const u16* __restrict__ Vt,
                 u16* __restrict__ ctx)
{
  const int KS = 2048, HD = 1024;
  __shared__ u16 Qs[64 * 80];
  __shared__ u16 Ks[64 * 80];
  __shared__ u16 Vts[64 * 72];   // [d][t]
  __shared__ u16 Ps[64 * 72];    // [q][t]

  const int qt = blockIdx.x, hh = blockIdx.y, bb = blockIdx.z;
  const int s0 = qt * 64;
  const int tid = threadIdx.x, w = tid >> 6, lane = tid & 63;
  const int mr = lane & 15, ko = (lane >> 4) * 8, rq = (lane >> 4) * 4;
  const int sr = tid >> 3, sc = (tid & 7) * 8;
  const int vrow = tid >> 2, vtc = (tid & 3) * 16;
  const float qsc = 0.022097086912079608f;  // 1/sqrt(2048)
  const int qg = s0 + w * 16 + mr;          // this lane's query row

#pragma unroll
  for (int p = 0; p < 2; ++p) {
    int row = p * 32 + sr;
    uint4 u = *(const uint4*)(QKb + (size_t)(bb * KS + s0 + row) * 2048 + hh * 64 + sc);
    *(uint4*)&Qs[row * 80 + sc] = u;
  }

  f32x4 accO[4];
#pragma unroll
  for (int j = 0; j < 4; ++j) { f32x4 z = {0.f,0.f,0.f,0.f}; accO[j] = z; }
  float lsum = 0.f;

  for (int c = 0; c < 9; ++c) {
    int tb = s0 - 256 + c * 64;
    if (tb < 0 || tb >= KS) continue;
    __syncthreads();
#pragma unroll
    for (int p = 0; p < 2; ++p) {
      int row = p * 32 + sr;
      uint4 uk = *(const uint4*)(QKb + (size_t)(bb * KS + tb + row) * 2048 + 1024 + hh * 64 + sc);
      *(uint4*)&Ks[row * 80 + sc] = uk;
    }
    {
      const u16* vsrc = Vt + (size_t)(hh * 64 + vrow) * 4096 + bb * KS + tb + vtc;
      *(uint4*)&Vts[vrow * 72 + vtc]     = *(const uint4*)vsrc;
      *(uint4*)&Vts[vrow * 72 + vtc + 8] = *(const uint4*)(vsrc + 8);
    }
    __syncthreads();

    // S = K Q^T (swapped): sacc[j] holds S[t= tb+j*16+rq+r][q= qg]
    f32x4 sacc[4];
#pragma unroll
    for (int j = 0; j < 4; ++j) { f32x4 z = {0.f,0.f,0.f,0.f}; sacc[j] = z; }
#pragma unroll
    for (int s = 0; s < 2; ++s) {
      bf16x8 aq = *(const bf16x8*)&Qs[(w * 16 + mr) * 80 + s * 32 + ko];
#pragma unroll
      for (int j = 0; j < 4; ++j) {
        bf16x8 bk = *(const bf16x8*)&Ks[(j * 16 + mr) * 80 + s * 32 + ko];
        sacc[j] = __builtin_amdgcn_mfma_f32_16x16x32_bf16(bk, aq, sacc[j], 0, 0, 0);
      }
    }

    // p = expf(s) (bounded scores); packed b64 P-writes; scalar l per lane
#pragma unroll
    for (int j = 0; j < 4; ++j) {
      int tgb = tb + j * 16 + rq;
      float p0, p1, p2, p3;
      {
        int d0 = qg - tgb;
        float s_ = sacc[j][0] * qsc;
        p0 = (d0 > 256 || d0 < -256) ? 0.f : __expf(s_);
        int d1 = d0 - 1; s_ = sacc[j][1] * qsc;
        p1 = (d1 > 256 || d1 < -256) ? 0.f : __expf(s_);
        int d2 = d0 - 2; s_ = sacc[j][2] * qsc;
        p2 = (d2 > 256 || d2 < -256) ? 0.f : __expf(s_);
        int d3 = d0 - 3; s_ = sacc[j][3] * qsc;
        p3 = (d3 > 256 || d3 < -256) ? 0.f : __expf(s_);
      }
      lsum += p0 + p1 + p2 + p3;
      uint32_t lo = (uint32_t)f2bf(p0) | ((uint32_t)f2bf(p1) << 16);
      uint32_t hi = (uint32_t)f2bf(p2) | ((uint32_t)f2bf(p3) << 16);
      *(uint2*)&Ps[(w * 16 + mr) * 72 + j * 16 + rq] = make_uint2(lo, hi);
    }
    // O += V^T P^T (swapped): accO[j] = O[d= j*16+rq+r][q= qg]
#pragma unroll
    for (int s = 0; s < 2; ++s) {
      bf16x8 ap = *(const bf16x8*)&Ps[(w * 16 + mr) * 72 + s * 32 + ko];
#pragma unroll
      for (int j = 0; j < 4; ++j) {
        bf16x8 bv = *(const bf16x8*)&Vts[(j * 16 + mr) * 72 + s * 32 + ko];
        accO[j] = __builtin_amdgcn_mfma_f32_16x16x32_bf16(bv, ap, accO[j], 0, 0, 0);
      }
    }
  }

  float l = lsum;
  l += __shfl_xor(l, 16, 64);
  l += __shfl_xor(l, 32, 64);
  float inv = 1.f / l;
  size_t base = (size_t)(bb * KS + qg) * HD + hh * 64;
#pragma unroll
  for (int j = 0; j < 4; ++j) {
    uint32_t lo = (uint32_t)f2bf(accO[j][0] * inv) | ((uint32_t)f2bf(accO[j][1] * inv) << 16);
    uint32_t hi = (uint32_t)f2bf(accO[j][2] * inv) | ((uint32_t)f2bf(accO[j][3] * inv) << 16);
    *(uint2*)(ctx + base + j * 16 + rq) = make_uint2(lo, hi);
  }
}

// ---------------------------------------------------------------------------
// LayerNorm(a_f32 + ab_bf16 + res) over D=1024.
// V=0: res fp32, out bf16 (LN1).  V=1: res bf16, out fp32 (LN2).
// ---------------------------------------------------------------------------
template<int V>
__global__ __launch_bounds__(256)
void ln_kernel(const float* __restrict__ a, const u16* __restrict__ ab,
               const void* __restrict__ res, const float* __restrict__ g,
               const float* __restrict__ be, void* __restrict__ out)
{
  __shared__ float red[8];
  const int row = blockIdx.x, tid = threadIdx.x;
  const int w = tid >> 6, lane = tid & 63;
  size_t base = (size_t)row * 1024 + tid * 4;
  float4 va = *(const float4*)(a + base);
  float v0 = va.x, v1 = va.y, v2 = va.z, v3 = va.w;
  {
    uint2 u = *(const uint2*)(ab + base);
    v0 += bf2f((u16)(u.x & 0xFFFFu));
    v1 += bf2f((u16)(u.x >> 16));
    v2 += bf2f((u16)(u.y & 0xFFFFu));
    v3 += bf2f((u16)(u.y >> 16));
  }
  if (V == 0) {
    float4 vb = *(const float4*)((const float*)res + base);
    v0 += vb.x; v1 += vb.y; v2 += vb.z; v3 += vb.w;
  } else {
    uint2 u = *(const uint2*)((const u16*)res + base);
    v0 += bf2f((u16)(u.x & 0xFFFFu));
    v1 += bf2f((u16)(u.x >> 16));
    v2 += bf2f((u16)(u.y & 0xFFFFu));
    v3 += bf2f((u16)(u.y >> 16));
  }
  float s1 = v0 + v1 + v2 + v3;
  float s2 = v0 * v0 + v1 * v1 + v2 * v2 + v3 * v3;
#pragma unroll
  for (int o = 32; o > 0; o >>= 1) {
    s1 += __shfl_xor(s1, o, 64);
    s2 += __shfl_xor(s2, o, 64);
  }
  if (lane == 0) { red[w] = s1; red[4 + w] = s2; }
  __syncthreads();
  s1 = red[0] + red[1] + red[2] + red[3];
  s2 = red[4] + red[5] + red[6] + red[7];
  float mu = s1 * (1.f / 1024.f);
  float var = s2 * (1.f / 1024.f) - mu * mu;
  float rs = rsqrtf(var + 1e-5f);
  float4 gv = *(const float4*)(g + tid * 4);
  float4 bv = *(const float4*)(be + tid * 4);
  float o0 = (v0 - mu) * rs * gv.x + bv.x;
  float o1 = (v1 - mu) * rs * gv.y + bv.y;
  float o2 = (v2 - mu) * rs * gv.z + bv.z;
  float o3 = (v3 - mu) * rs * gv.w + bv.w;
  if (V == 0) {
    uint32_t lo = (uint32_t)f2bf(o0) | ((uint32_t)f2bf(o1) << 16);
    uint32_t hi = (uint32_t)f2bf(o2) | ((uint32_t)f2bf(o3) << 16);
    *(uint2*)((u16*)out + base) = make_uint2(lo, hi);
  } else {
    float4 ov; ov.x = o0; ov.y = o1; ov.z = o2; ov.w = o3;
    *(float4*)((float*)out + base) = ov;
  }
}

// ---------------------------------------------------------------------------
// ws layout (64 MiB), MiB offsets, lifetime-verified:
//  [0,8)   W1T (prep->G3)        -> Y1 bf16 (G4->LN2)
//  [8,16)  xb (prep->G1)         -> X1b bf16 (LN1->LN2)
//  [16,22) WqkvT (prep->G1)
//  [22,24) WoT (prep->G2)
//  [24,40) QKb (G1->attn)        -> SA0 fp32 (G2->LN1)  -> Hb[lo] (G3->G4)
//  [40,48) Vt  (G1->attn)        -> SA1 bf16 (G2->LN1)  -> Hb[mid]
//  [48,56) bqkv (prep->G1)       -> Cb (attn->G2)       -> Hb[hi]
//  [56,64) W2T (prep->G4)
// ---------------------------------------------------------------------------
extern "C" void kernel_launch(void* const* d_in, const int* in_sizes, int n_in,
                              void* d_out, int out_size, void* d_ws, size_t ws_size,
                              hipStream_t stream)
{
  (void)in_sizes; (void)n_in; (void)out_size; (void)ws_size;
  const float* x   = (const float*)d_in[0];
  const float* Wq  = (const float*)d_in[1];
  const float* bq  = (const float*)d_in[2];
  const float* Wk  = (const float*)d_in[3];
  const float* bk  = (const float*)d_in[4];
  const float* Wv  = (const float*)d_in[5];
  const float* bv  = (const float*)d_in[6];
  const float* Wo  = (const float*)d_in[7];
  const float* bo  = (const float*)d_in[8];
  const float* W1  = (const float*)d_in[9];
  const float* b1  = (const float*)d_in[10];
  const float* W2  = (const float*)d_in[11];
  const float* b2  = (const float*)d_in[12];
  const float* g1  = (const float*)d_in[13];
  const float* be1 = (const float*)d_in[14];
  const float* g2  = (const float*)d_in[15];
  const float* be2 = (const float*)d_in[16];

  char* ws = (char*)d_ws;
  const size_t MB = 1048576;
  u16*   W1T   = (u16*)(ws + 0 * MB);
  u16*   Y1    = (u16*)(ws + 0 * MB);
  u16*   xb    = (u16*)(ws + 8 * MB);
  u16*   X1b   = (u16*)(ws + 8 * MB);
  u16*   WqkvT = (u16*)(ws + 16 * MB);
  u16*   WoT   = (u16*)(ws + 22 * MB);
  u16*   QKb   = (u16*)(ws + 24 * MB);
  float* SA0   = (float*)(ws + 24 * MB);
  u16*   Hb    = (u16*)(ws + 24 * MB);
  u16*   Vt    = (u16*)(ws + 40 * MB);
  u16*   SA1   = (u16*)(ws + 40 * MB);
  float* bqkv  = (float*)(ws + 48 * MB);
  u16*   Cb    = (u16*)(ws + 48 * MB);
  u16*   W2T   = (u16*)(ws + 56 * MB);
  float* yout  = (float*)d_out;

  dim3 blk(256);
  // fused prep (one launch)
  prep_kernel<<<7180, blk, 0, stream>>>(Wq, Wk, Wv, Wo, W1, W2, x, bq, bk, bv,
                                        WqkvT, WoT, W1T, W2T, xb, bqkv);
  // G1: fused QKV projection (Q,K -> QKb; V -> Vt transposed)
  gemm_kernel<0><<<dim3(24, 32, 1), blk, 0, stream>>>(xb, WqkvT, bqkv, QKb, Vt, 3072, 1024, 1024);
  // attention
  attn_kernel<<<dim3(32, 16, 2), blk, 0, stream>>>(QKb, Vt, Cb);
  // G2: sa = ctx @ Wo + bo, split-K=2
  gemm_kernel<2><<<dim3(8, 32, 2), blk, 0, stream>>>(Cb, WoT, bo, SA0, SA1, 1024, 1024, 512);
  // LN1: x1 = LN(sa0 + sa1 + x) -> bf16
  ln_kernel<0><<<4096, blk, 0, stream>>>(SA0, SA1, x, g1, be1, X1b);
  // G3: h = gelu(x1 @ W1 + b1)
  gemm_kernel<1><<<dim3(32, 32, 1), blk, 0, stream>>>(X1b, W1T, b1, Hb, nullptr, 4096, 1024, 1024);
  // G4: y = h @ W2 + b2, split-K=2 -> d_out fp32 + Y1 bf16
  gemm_kernel<2><<<dim3(8, 32, 2), blk, 0, stream>>>(Hb, W2T, b2, yout, Y1, 1024, 4096, 2048);
  // LN2: out = LN(y0 + y1 + x1) in place
  ln_kernel<1><<<4096, blk, 0, stream>>>(yout, Y1, X1b, g2, be2, yout);
}